// Round 1
// baseline (1319.083 us; speedup 1.0000x reference)
//
#include <hip/hip_runtime.h>
#include <math.h>

#define LN_EPS 1e-5f
#define NEG_SLOPE 0.2f

// ---- monotonic float<->uint encoding for atomicMax on floats ----
__device__ inline unsigned fenc(float f) {
    unsigned u = __float_as_uint(f);
    return (u & 0x80000000u) ? ~u : (u | 0x80000000u);
}
__device__ inline float fdec(unsigned u) {
    return (u & 0x80000000u) ? __uint_as_float(u & 0x7fffffffu)
                             : __uint_as_float(~u);
}

// Y[row, 0:M] = X[row, 0:K] @ W[0:K, 0:M].  One block per row, 128 threads.
__global__ void gemm_block(const float* __restrict__ X, const float* __restrict__ W,
                           float* __restrict__ Y, int N, int K, int M) {
    __shared__ float xs[128];
    int row = blockIdx.x;
    if (row >= N) return;
    int t = threadIdx.x;
    if (t < K) xs[t] = X[(size_t)row * K + t];
    __syncthreads();
    if (t < M) {
        float acc = 0.f;
#pragma unroll 8
        for (int k = 0; k < K; ++k) acc += xs[k] * W[(size_t)k * M + t];
        Y[(size_t)row * M + t] = acc;
    }
}

// a_s[n,h] = sum_c h[n,h,c]*att_src[h,c]; a_d likewise. One thread per (n,h).
__global__ void att_kernel(const float* __restrict__ Hf, const float* __restrict__ AS,
                           const float* __restrict__ AD, float* __restrict__ a_s,
                           float* __restrict__ a_d, int N, int HH, int C) {
    int i = blockIdx.x * blockDim.x + threadIdx.x;
    if (i >= N * HH) return;
    int n = i / HH, h = i % HH;
    const float* hp = Hf + (size_t)n * HH * C + (size_t)h * C;
    const float* asp = AS + (size_t)h * C;
    const float* adp = AD + (size_t)h * C;
    float s1 = 0.f, s2 = 0.f;
    for (int c = 0; c < C; ++c) {
        float v = hp[c];
        s1 += v * asp[c];
        s2 += v * adp[c];
    }
    a_s[i] = s1;
    a_d[i] = s2;
}

// pass A: alpha = leaky_relu(a_s[src]+a_d[dst]); atomicMax into amax[dst,h]
__global__ void edge_passA(const int* __restrict__ ei, int E, int N, int HH,
                           const float* __restrict__ a_s, const float* __restrict__ a_d,
                           float* __restrict__ alpha, unsigned* __restrict__ amax) {
    int e = blockIdx.x * blockDim.x + threadIdx.x;
    int T = E + N;
    if (e >= T) return;
    int s = (e < E) ? ei[e] : (e - E);
    int d = (e < E) ? ei[E + e] : (e - E);
    for (int h = 0; h < HH; ++h) {
        float al = a_s[s * HH + h] + a_d[d * HH + h];
        al = (al > 0.f) ? al : NEG_SLOPE * al;
        alpha[(size_t)e * HH + h] = al;
        atomicMax(&amax[d * HH + h], fenc(al));
    }
}

// pass B: alpha = exp(alpha - amax[dst]); atomicAdd into denom[dst,h]
__global__ void edge_passB(const int* __restrict__ ei, int E, int N, int HH,
                           float* __restrict__ alpha, const unsigned* __restrict__ amax,
                           float* __restrict__ denom) {
    int e = blockIdx.x * blockDim.x + threadIdx.x;
    int T = E + N;
    if (e >= T) return;
    int d = (e < E) ? ei[E + e] : (e - E);
    for (int h = 0; h < HH; ++h) {
        float m = fdec(amax[d * HH + h]);
        float v = expf(alpha[(size_t)e * HH + h] - m);
        alpha[(size_t)e * HH + h] = v;
        atomicAdd(&denom[d * HH + h], v);
    }
}

// pass C: out[dst, t] += (alpha/denom) * h[src, t].  One thread per (edge, t).
__global__ void edge_passC(const int* __restrict__ ei, int E, int N, int HH, int C,
                           const float* __restrict__ alpha, const float* __restrict__ denom,
                           const float* __restrict__ Hf, float* __restrict__ out) {
    long long i = (long long)blockIdx.x * blockDim.x + threadIdx.x;
    int HC = HH * C;
    long long T = (long long)(E + N) * HC;
    if (i >= T) return;
    int e = (int)(i / HC);
    int t = (int)(i % HC);
    int h = t / C;
    int s = (e < E) ? ei[e] : (e - E);
    int d = (e < E) ? ei[E + e] : (e - E);
    float coef = alpha[(size_t)e * HH + h] / (denom[d * HH + h] + 1e-16f);
    atomicAdd(&out[(size_t)d * HC + t], coef * Hf[(size_t)s * HC + t]);
}

// bias + LayerNorm + ELU, one block per node, blockDim = F (64 or 128)
__global__ void post_ln_elu(const float* __restrict__ out, const float* __restrict__ bias,
                            const float* __restrict__ g, const float* __restrict__ be,
                            float* __restrict__ feat, int F) {
    __shared__ float red[128];
    int n = blockIdx.x;
    int t = threadIdx.x;
    float v = out[(size_t)n * F + t] + bias[t];
    red[t] = v;
    __syncthreads();
    for (int s = F >> 1; s > 0; s >>= 1) {
        if (t < s) red[t] += red[t + s];
        __syncthreads();
    }
    float mu = red[0] / F;
    __syncthreads();
    float dv = v - mu;
    red[t] = dv * dv;
    __syncthreads();
    for (int s = F >> 1; s > 0; s >>= 1) {
        if (t < s) red[t] += red[t + s];
        __syncthreads();
    }
    float var = red[0] / F;
    float y = dv * rsqrtf(var + LN_EPS) * g[t] + be[t];
    y = (y > 0.f) ? y : expm1f(y);
    feat[(size_t)n * F + t] = y;
}

// final bias + 2-class log_softmax
__global__ void final_lsm(const float* __restrict__ out, const float* __restrict__ b3,
                          float* __restrict__ y, int N) {
    int n = blockIdx.x * blockDim.x + threadIdx.x;
    if (n >= N) return;
    float h0 = out[2 * n + 0] + b3[0];
    float h1 = out[2 * n + 1] + b3[1];
    float m = fmaxf(h0, h1);
    float l = m + logf(expf(h0 - m) + expf(h1 - m));
    y[2 * n + 0] = h0 - l;
    y[2 * n + 1] = h1 - l;
}

static void run_layer(const float* X, const int* ei, int N, int E,
                      const float* W, const float* AS, const float* AD,
                      int K, int HH, int C,
                      float* h, float* as_, float* ad_,
                      unsigned* amax, float* denom, float* alpha, float* out,
                      hipStream_t stream) {
    int M = HH * C;
    gemm_block<<<N, 128, 0, stream>>>(X, W, h, N, K, M);
    int nh = N * HH;
    att_kernel<<<(nh + 255) / 256, 256, 0, stream>>>(h, AS, AD, as_, ad_, N, HH, C);
    hipMemsetAsync(amax, 0, (size_t)nh * sizeof(unsigned), stream);
    hipMemsetAsync(denom, 0, (size_t)nh * sizeof(float), stream);
    hipMemsetAsync(out, 0, (size_t)N * M * sizeof(float), stream);
    int T = E + N;
    edge_passA<<<(T + 255) / 256, 256, 0, stream>>>(ei, E, N, HH, as_, ad_, alpha, amax);
    edge_passB<<<(T + 255) / 256, 256, 0, stream>>>(ei, E, N, HH, alpha, amax, denom);
    long long TC = (long long)T * M;
    edge_passC<<<(int)((TC + 255) / 256), 256, 0, stream>>>(ei, E, N, HH, C, alpha, denom, h, out);
}

extern "C" void kernel_launch(void* const* d_in, const int* in_sizes, int n_in,
                              void* d_out, int out_size, void* d_ws, size_t ws_size,
                              hipStream_t stream) {
    const float* x   = (const float*)d_in[0];
    const int*   ei  = (const int*)d_in[1];
    const float* W1  = (const float*)d_in[2];
    const float* as1 = (const float*)d_in[3];
    const float* ad1 = (const float*)d_in[4];
    const float* b1  = (const float*)d_in[5];
    const float* g1  = (const float*)d_in[6];
    const float* be1 = (const float*)d_in[7];
    const float* W2  = (const float*)d_in[8];
    const float* as2 = (const float*)d_in[9];
    const float* ad2 = (const float*)d_in[10];
    const float* b2  = (const float*)d_in[11];
    const float* g2  = (const float*)d_in[12];
    const float* be2 = (const float*)d_in[13];
    const float* W3  = (const float*)d_in[14];
    const float* as3 = (const float*)d_in[15];
    const float* ad3 = (const float*)d_in[16];
    const float* b3  = (const float*)d_in[17];

    int N = in_sizes[0] / 128;
    int E = in_sizes[1] / 2;

    float* base  = (float*)d_ws;
    float* h     = base;                          // N*128
    float* feat  = h + (size_t)N * 128;           // N*128
    float* outb  = feat + (size_t)N * 128;        // N*128
    float* as_   = outb + (size_t)N * 128;        // N*2
    float* ad_   = as_ + (size_t)N * 2;           // N*2
    float* denom = ad_ + (size_t)N * 2;           // N*2
    unsigned* amax = (unsigned*)(denom + (size_t)N * 2);  // N*2
    float* alpha = (float*)(amax + (size_t)N * 2);        // (E+N)*2

    // layer 1: 128 -> (2 heads x 64), concat -> 128
    run_layer(x, ei, N, E, W1, as1, ad1, 128, 2, 64, h, as_, ad_, amax, denom, alpha, outb, stream);
    post_ln_elu<<<N, 128, 0, stream>>>(outb, b1, g1, be1, feat, 128);

    // layer 2: 128 -> (2 heads x 32), concat -> 64
    run_layer(feat, ei, N, E, W2, as2, ad2, 128, 2, 32, h, as_, ad_, amax, denom, alpha, outb, stream);
    post_ln_elu<<<N, 64, 0, stream>>>(outb, b2, g2, be2, feat, 64);

    // layer 3: 64 -> (1 head x 2), concat -> 2
    run_layer(feat, ei, N, E, W3, as3, ad3, 64, 1, 2, h, as_, ad_, amax, denom, alpha, outb, stream);
    final_lsm<<<(N + 255) / 256, 256, 0, stream>>>(outb, b3, (float*)d_out, N);
}

// Round 2
// 586.141 us; speedup vs baseline: 2.2505x; 2.2505x over previous
//
#include <hip/hip_runtime.h>
#include <math.h>

#define LN_EPS 1e-5f
#define NEG_SLOPE 0.2f

// ---------------- CSR build ----------------

__global__ void hist_kernel(const int* __restrict__ ei, int E, int N, int* __restrict__ cnt) {
    int e = blockIdx.x * blockDim.x + threadIdx.x;
    if (e >= E + N) return;
    int d = (e < E) ? ei[E + e] : (e - E);
    atomicAdd(&cnt[d], 1);
}

// inclusive scan of cnt per 512-block; partial = within-block inclusive, bsum = block total
__global__ void scan1_kernel(const int* __restrict__ cnt, int* __restrict__ partial,
                             int* __restrict__ bsum, int N) {
    __shared__ int sh[512];
    int t = threadIdx.x;
    int i = blockIdx.x * 512 + t;
    int v = (i < N) ? cnt[i] : 0;
    sh[t] = v;
    __syncthreads();
    for (int off = 1; off < 512; off <<= 1) {
        int a = (t >= off) ? sh[t - off] : 0;
        __syncthreads();
        sh[t] += a;
        __syncthreads();
    }
    if (i < N) partial[i] = sh[t];
    if (t == 511) bsum[blockIdx.x] = sh[511];
}

// exclusive scan of bsum in-place (nb <= 512)
__global__ void scan2_kernel(int* __restrict__ bsum, int nb) {
    __shared__ int sh[512];
    int t = threadIdx.x;
    int v = (t < nb) ? bsum[t] : 0;
    sh[t] = v;
    __syncthreads();
    for (int off = 1; off < 512; off <<= 1) {
        int a = (t >= off) ? sh[t - off] : 0;
        __syncthreads();
        sh[t] += a;
        __syncthreads();
    }
    if (t < nb) bsum[t] = sh[t] - v;
}

__global__ void scan3_kernel(const int* __restrict__ partial, const int* __restrict__ boff,
                             const int* __restrict__ cnt, int* __restrict__ row_start,
                             int* __restrict__ cursor, int N) {
    int i = blockIdx.x * blockDim.x + threadIdx.x;
    if (i >= N) return;
    int incl = partial[i] + boff[i >> 9];
    int st = incl - cnt[i];
    row_start[i] = st;
    cursor[i] = st;
}

__global__ void scatter_kernel(const int* __restrict__ ei, int E, int N,
                               int* __restrict__ cursor, int* __restrict__ col) {
    int e = blockIdx.x * blockDim.x + threadIdx.x;
    if (e >= E + N) return;
    int s = (e < E) ? ei[e] : (e - E);
    int d = (e < E) ? ei[E + e] : (e - E);
    int pos = atomicAdd(&cursor[d], 1);
    col[pos] = s;
}

// ---------------- GEMM + attention-logit fusion ----------------
// Y[row,:] = X[row,:] @ W ; a_s[row,h] = sum_c Y[row,h*C+c]*AS[h*C+c]; a_d likewise.
template <int K, int M, int HH>
__launch_bounds__(128)
__global__ void gemm_att(const float* __restrict__ X, const float* __restrict__ W,
                         const float* __restrict__ AS, const float* __restrict__ AD,
                         float* __restrict__ Y, float* __restrict__ a_s,
                         float* __restrict__ a_d, int N) {
    constexpr int C = M / HH;
    __shared__ float xs[K];
    __shared__ float red[128];
    int row = blockIdx.x;
    int t = threadIdx.x;
    if (t < K) xs[t] = X[(size_t)row * K + t];
    __syncthreads();
    float y = 0.f;
    if (t < M) {
#pragma unroll 8
        for (int k = 0; k < K; ++k) y += xs[k] * W[k * M + t];
        Y[(size_t)row * M + t] = y;
    }
    red[t] = (t < M) ? y * AS[t] : 0.f;
    __syncthreads();
#pragma unroll
    for (int st = C / 2; st > 0; st >>= 1) {
        if (t < M && (t & (C - 1)) < st) red[t] += red[t + st];
        __syncthreads();
    }
    if (t < M && (t & (C - 1)) == 0) a_s[row * HH + t / C] = red[t];
    __syncthreads();
    red[t] = (t < M) ? y * AD[t] : 0.f;
    __syncthreads();
#pragma unroll
    for (int st = C / 2; st > 0; st >>= 1) {
        if (t < M && (t & (C - 1)) < st) red[t] += red[t + st];
        __syncthreads();
    }
    if (t < M && (t & (C - 1)) == 0) a_d[row * HH + t / C] = red[t];
}

// ---------------- fused GAT aggregation: one wave per dst node ----------------
// softmax over incoming edges (online, no atomics) + weighted gather + epilogue
// MODE 0: bias+LayerNorm+ELU -> outp[N,M]; MODE 1: bias+log_softmax (M==2) -> outp[N,2]
template <int HH, int C, int MODE>
__launch_bounds__(256)
__global__ void gat_gather(const int* __restrict__ col, const int* __restrict__ row_start,
                           const int* __restrict__ cnt, const float* __restrict__ Hf,
                           const float* __restrict__ a_s, const float* __restrict__ a_d,
                           const float* __restrict__ bias, const float* __restrict__ gw,
                           const float* __restrict__ bw, float* __restrict__ outp, int N) {
    constexpr int M = HH * C;
    constexpr int FPL = (M + 63) / 64;  // features per lane
    int wid = blockIdx.x * (blockDim.x >> 6) + (threadIdx.x >> 6);
    int lane = threadIdx.x & 63;
    if (wid >= N) return;
    const int d = wid;
    const int start = row_start[d];
    const int deg = cnt[d];

    float adH[HH];
#pragma unroll
    for (int h = 0; h < HH; ++h) adH[h] = a_d[d * HH + h];

    // phase 1: online softmax stats over the segment
    float m[HH], s[HH];
#pragma unroll
    for (int h = 0; h < HH; ++h) { m[h] = -INFINITY; s[h] = 0.f; }
    for (int base = 0; base < deg; base += 64) {
        int j = base + lane;
        if (j < deg) {
            int src = col[start + j];
#pragma unroll
            for (int h = 0; h < HH; ++h) {
                float lg = a_s[src * HH + h] + adH[h];
                lg = (lg > 0.f) ? lg : NEG_SLOPE * lg;
                float nm = fmaxf(m[h], lg);
                s[h] = s[h] * __expf(m[h] - nm) + __expf(lg - nm);
                m[h] = nm;
            }
        }
    }
#pragma unroll
    for (int off = 32; off > 0; off >>= 1) {
#pragma unroll
        for (int h = 0; h < HH; ++h) {
            float om = __shfl_xor(m[h], off);
            float os = __shfl_xor(s[h], off);
            float nm = fmaxf(m[h], om);
            float t1 = (m[h] == -INFINITY) ? 0.f : s[h] * __expf(m[h] - nm);
            float t2 = (om == -INFINITY) ? 0.f : os * __expf(om - nm);
            m[h] = nm;
            s[h] = t1 + t2;
        }
    }

    // phase 2: weighted gather
    const int t0 = lane * FPL;
    const bool active = (t0 < M);
    const int hl = active ? (t0 / C) : 0;
    const float mh = m[hl];
    const float invh = 1.f / (s[hl] + 1e-16f);
    const float adh = adH[hl];
    float acc[FPL] = {};
    for (int j = 0; j < deg; ++j) {
        int src = col[start + j];
        float lg = a_s[src * HH + hl] + adh;
        lg = (lg > 0.f) ? lg : NEG_SLOPE * lg;
        float coef = __expf(lg - mh) * invh;
        const float* hp = Hf + (size_t)src * M + t0;
        if constexpr (FPL == 2) {
            float2 hv = *reinterpret_cast<const float2*>(hp);
            acc[0] += coef * hv.x;
            acc[1] += coef * hv.y;
        } else {
            if (active) acc[0] += coef * hp[0];
        }
    }

    if constexpr (MODE == 0) {
        float v[FPL];
        float ls = 0.f;
#pragma unroll
        for (int jj = 0; jj < FPL; ++jj) {
            v[jj] = acc[jj] + bias[t0 + jj];
            ls += v[jj];
        }
#pragma unroll
        for (int off = 32; off > 0; off >>= 1) ls += __shfl_xor(ls, off);
        float mu = ls * (1.0f / M);
        float lv = 0.f;
#pragma unroll
        for (int jj = 0; jj < FPL; ++jj) {
            float dv = v[jj] - mu;
            lv += dv * dv;
        }
#pragma unroll
        for (int off = 32; off > 0; off >>= 1) lv += __shfl_xor(lv, off);
        float rstd = rsqrtf(lv * (1.0f / M) + LN_EPS);
#pragma unroll
        for (int jj = 0; jj < FPL; ++jj) {
            float y = (v[jj] - mu) * rstd * gw[t0 + jj] + bw[t0 + jj];
            v[jj] = (y > 0.f) ? y : expm1f(y);
        }
        if constexpr (FPL == 2) {
            *reinterpret_cast<float2*>(outp + (size_t)d * M + t0) = make_float2(v[0], v[1]);
        } else {
            outp[(size_t)d * M + t0] = v[0];
        }
    } else {
        // final layer: M == 2, bias + log_softmax
        float v = active ? (acc[0] + bias[t0]) : 0.f;
        float o = __shfl_xor(v, 1);
        if (active) {
            float mx = fmaxf(v, o);
            float l = mx + logf(expf(v - mx) + expf(o - mx));
            outp[(size_t)d * 2 + t0] = v - l;
        }
    }
}

extern "C" void kernel_launch(void* const* d_in, const int* in_sizes, int n_in,
                              void* d_out, int out_size, void* d_ws, size_t ws_size,
                              hipStream_t stream) {
    const float* x   = (const float*)d_in[0];
    const int*   ei  = (const int*)d_in[1];
    const float* W1  = (const float*)d_in[2];
    const float* as1 = (const float*)d_in[3];
    const float* ad1 = (const float*)d_in[4];
    const float* b1  = (const float*)d_in[5];
    const float* g1  = (const float*)d_in[6];
    const float* be1 = (const float*)d_in[7];
    const float* W2  = (const float*)d_in[8];
    const float* as2 = (const float*)d_in[9];
    const float* ad2 = (const float*)d_in[10];
    const float* b2  = (const float*)d_in[11];
    const float* g2  = (const float*)d_in[12];
    const float* be2 = (const float*)d_in[13];
    const float* W3  = (const float*)d_in[14];
    const float* as3 = (const float*)d_in[15];
    const float* ad3 = (const float*)d_in[16];
    const float* b3  = (const float*)d_in[17];

    int N = in_sizes[0] / 128;
    int E = in_sizes[1] / 2;
    int T = E + N;

    float* fbase = (float*)d_ws;
    float* h    = fbase;                          // N*128
    float* feat = h + (size_t)N * 128;            // N*128
    float* a_s  = feat + (size_t)N * 128;         // N*2
    float* a_d  = a_s + (size_t)N * 2;            // N*2
    int* cnt       = (int*)(a_d + (size_t)N * 2); // N
    int* partial   = cnt + N;                     // N
    int* bsum      = partial + N;                 // 512
    int* row_start = bsum + 512;                  // N
    int* cursor    = row_start + N;               // N
    int* col       = cursor + N;                  // E+N

    // ---- CSR build (dst-grouped, self-loops included) ----
    hipMemsetAsync(cnt, 0, (size_t)N * sizeof(int), stream);
    hist_kernel<<<(T + 255) / 256, 256, 0, stream>>>(ei, E, N, cnt);
    int nb = (N + 511) / 512;
    scan1_kernel<<<nb, 512, 0, stream>>>(cnt, partial, bsum, N);
    scan2_kernel<<<1, 512, 0, stream>>>(bsum, nb);
    scan3_kernel<<<(N + 255) / 256, 256, 0, stream>>>(partial, bsum, cnt, row_start, cursor, N);
    scatter_kernel<<<(T + 255) / 256, 256, 0, stream>>>(ei, E, N, cursor, col);

    int gblocks = (N + 3) / 4;

    // ---- layer 1: 128 -> (2 x 64), concat 128, LN+ELU ----
    gemm_att<128, 128, 2><<<N, 128, 0, stream>>>(x, W1, as1, ad1, h, a_s, a_d, N);
    gat_gather<2, 64, 0><<<gblocks, 256, 0, stream>>>(col, row_start, cnt, h, a_s, a_d,
                                                      b1, g1, be1, feat, N);

    // ---- layer 2: 128 -> (2 x 32), concat 64, LN+ELU ----
    gemm_att<128, 64, 2><<<N, 128, 0, stream>>>(feat, W2, as2, ad2, h, a_s, a_d, N);
    gat_gather<2, 32, 0><<<gblocks, 256, 0, stream>>>(col, row_start, cnt, h, a_s, a_d,
                                                      b2, g2, be2, feat, N);

    // ---- layer 3: 64 -> (1 x 2), bias + log_softmax ----
    gemm_att<64, 2, 1><<<N, 128, 0, stream>>>(feat, W3, as3, ad3, h, a_s, a_d, N);
    gat_gather<1, 2, 1><<<gblocks, 256, 0, stream>>>(col, row_start, cnt, h, a_s, a_d,
                                                     b3, nullptr, nullptr, (float*)d_out, N);
}

// Round 3
// 451.061 us; speedup vs baseline: 2.9244x; 1.2995x over previous
//
#include <hip/hip_runtime.h>
#include <math.h>

#define LN_EPS 1e-5f
#define NEG_SLOPE 0.2f

// ---------------- CSR build ----------------

__global__ void hist_kernel(const int* __restrict__ ei, int E, int N, int* __restrict__ cnt) {
    int e = blockIdx.x * blockDim.x + threadIdx.x;
    if (e >= E + N) return;
    int d = (e < E) ? ei[E + e] : (e - E);
    atomicAdd(&cnt[d], 1);
}

__global__ void scan1_kernel(const int* __restrict__ cnt, int* __restrict__ partial,
                             int* __restrict__ bsum, int N) {
    __shared__ int sh[512];
    int t = threadIdx.x;
    int i = blockIdx.x * 512 + t;
    int v = (i < N) ? cnt[i] : 0;
    sh[t] = v;
    __syncthreads();
    for (int off = 1; off < 512; off <<= 1) {
        int a = (t >= off) ? sh[t - off] : 0;
        __syncthreads();
        sh[t] += a;
        __syncthreads();
    }
    if (i < N) partial[i] = sh[t];
    if (t == 511) bsum[blockIdx.x] = sh[511];
}

__global__ void scan2_kernel(int* __restrict__ bsum, int nb) {
    __shared__ int sh[512];
    int t = threadIdx.x;
    int v = (t < nb) ? bsum[t] : 0;
    sh[t] = v;
    __syncthreads();
    for (int off = 1; off < 512; off <<= 1) {
        int a = (t >= off) ? sh[t - off] : 0;
        __syncthreads();
        sh[t] += a;
        __syncthreads();
    }
    if (t < nb) bsum[t] = sh[t] - v;
}

__global__ void scan3_kernel(const int* __restrict__ partial, const int* __restrict__ boff,
                             const int* __restrict__ cnt, int* __restrict__ row_start,
                             int* __restrict__ cursor, int N) {
    int i = blockIdx.x * blockDim.x + threadIdx.x;
    if (i >= N) return;
    int incl = partial[i] + boff[i >> 9];
    int st = incl - cnt[i];
    row_start[i] = st;
    cursor[i] = st;
}

__global__ void scatter_kernel(const int* __restrict__ ei, int E, int N,
                               int* __restrict__ cursor, int* __restrict__ col) {
    int e = blockIdx.x * blockDim.x + threadIdx.x;
    if (e >= E + N) return;
    int s = (e < E) ? ei[e] : (e - E);
    int d = (e < E) ? ei[E + e] : (e - E);
    int pos = atomicAdd(&cursor[d], 1);
    col[pos] = s;
}

// ---------------- register-tiled GEMM: Y[N,M] = X[N,K] @ W[K,M] ----------------
// 64 rows/block, thread computes 8 rows x 4 cols in registers, K chunked by 64.
template <int K, int M>
__launch_bounds__(256)
__global__ void gemm_tile(const float* __restrict__ X, const float* __restrict__ W,
                          float* __restrict__ Y, int N) {
    constexpr int BR = 64, CT = 4, RT = 8, KC = 64;
    constexpr int TC = M / CT;            // 32 (M=128) or 16 (M=64)
    constexpr int NT = TC * (BR / RT);    // 256 or 128
    __shared__ float Xs[BR][KC];
    __shared__ float Ws[KC][M];
    int tid = threadIdx.x;
    if (tid >= NT) return;
    int tc = tid % TC, tr = tid / TC;
    int row0 = blockIdx.x * BR;
    float acc[RT][CT] = {};
#pragma unroll
    for (int kc = 0; kc < K; kc += KC) {
        constexpr int XV = (BR * KC / 4) / NT;
#pragma unroll
        for (int i = 0; i < XV; ++i) {
            int f = tid + i * NT;
            int r = f / (KC / 4), c4 = f % (KC / 4);
            int row = row0 + r;
            float4 v = (row < N) ? *reinterpret_cast<const float4*>(&X[(size_t)row * K + kc + c4 * 4])
                                 : make_float4(0.f, 0.f, 0.f, 0.f);
            *reinterpret_cast<float4*>(&Xs[r][c4 * 4]) = v;
        }
        constexpr int WV = (KC * M / 4) / NT;
#pragma unroll
        for (int i = 0; i < WV; ++i) {
            int f = tid + i * NT;
            int kk = f / (M / 4), c4 = f % (M / 4);
            *reinterpret_cast<float4*>(&Ws[kk][c4 * 4]) =
                *reinterpret_cast<const float4*>(&W[(size_t)(kc + kk) * M + c4 * 4]);
        }
        __syncthreads();
#pragma unroll 4
        for (int k = 0; k < KC; ++k) {
            float4 wv = *reinterpret_cast<const float4*>(&Ws[k][tc * 4]);
#pragma unroll
            for (int rr = 0; rr < RT; ++rr) {
                float xv = Xs[tr * RT + rr][k];
                acc[rr][0] += xv * wv.x;
                acc[rr][1] += xv * wv.y;
                acc[rr][2] += xv * wv.z;
                acc[rr][3] += xv * wv.w;
            }
        }
        __syncthreads();
    }
#pragma unroll
    for (int rr = 0; rr < RT; ++rr) {
        int row = row0 + tr * RT + rr;
        if (row < N) {
            *reinterpret_cast<float4*>(&Y[(size_t)row * M + tc * 4]) =
                make_float4(acc[rr][0], acc[rr][1], acc[rr][2], acc[rr][3]);
        }
    }
}

// ---------------- attention logits: a_s[n,h] = sum_c h[n,h,c]*AS[h,c] ----------------
// C==64 (HH==2): one wave per (row, head).  C==32 (HH==2): one wave per row.
template <int HH, int C>
__launch_bounds__(256)
__global__ void att_red(const float* __restrict__ Hf, const float* __restrict__ AS,
                        const float* __restrict__ AD, float* __restrict__ a_s,
                        float* __restrict__ a_d, int N) {
    int wid = blockIdx.x * (blockDim.x >> 6) + (threadIdx.x >> 6);
    int lane = threadIdx.x & 63;
    if constexpr (C == 64) {
        int row = wid >> 1, head = wid & 1;
        if (row >= N) return;
        float v = Hf[(size_t)row * 128 + head * 64 + lane];
        float s1 = v * AS[head * 64 + lane];
        float s2 = v * AD[head * 64 + lane];
#pragma unroll
        for (int off = 32; off > 0; off >>= 1) {
            s1 += __shfl_xor(s1, off);
            s2 += __shfl_xor(s2, off);
        }
        if (lane == 0) {
            a_s[row * 2 + head] = s1;
            a_d[row * 2 + head] = s2;
        }
    } else {
        int row = wid;
        if (row >= N) return;
        float v = Hf[(size_t)row * 64 + lane];
        float s1 = v * AS[lane];
        float s2 = v * AD[lane];
#pragma unroll
        for (int off = 16; off > 0; off >>= 1) {
            s1 += __shfl_xor(s1, off);
            s2 += __shfl_xor(s2, off);
        }
        if ((lane & 31) == 0) {
            a_s[row * 2 + (lane >> 5)] = s1;
            a_d[row * 2 + (lane >> 5)] = s2;
        }
    }
}

// ---------------- layer 3 transform: h3[N,2] = X[N,64] @ W3[64,2], + logits ----------------
__launch_bounds__(256)
__global__ void l3_transform(const float* __restrict__ X, const float* __restrict__ W3,
                             const float* __restrict__ as3, const float* __restrict__ ad3,
                             float* __restrict__ h3, float* __restrict__ a_s,
                             float* __restrict__ a_d, int N) {
    int n = blockIdx.x * blockDim.x + threadIdx.x;
    if (n >= N) return;
    const float4* xp = reinterpret_cast<const float4*>(&X[(size_t)n * 64]);
    float h0 = 0.f, h1 = 0.f;
#pragma unroll
    for (int i = 0; i < 16; ++i) {
        float4 x4 = xp[i];
        int k = i * 4;
        h0 += x4.x * W3[(k + 0) * 2] + x4.y * W3[(k + 1) * 2] +
              x4.z * W3[(k + 2) * 2] + x4.w * W3[(k + 3) * 2];
        h1 += x4.x * W3[(k + 0) * 2 + 1] + x4.y * W3[(k + 1) * 2 + 1] +
              x4.z * W3[(k + 2) * 2 + 1] + x4.w * W3[(k + 3) * 2 + 1];
    }
    h3[(size_t)n * 2 + 0] = h0;
    h3[(size_t)n * 2 + 1] = h1;
    a_s[n] = h0 * as3[0] + h1 * as3[1];
    a_d[n] = h0 * ad3[0] + h1 * ad3[1];
}

// ---------------- fused GAT aggregation: one wave per dst node ----------------
template <int HH, int C, int MODE>
__launch_bounds__(256)
__global__ void gat_gather(const int* __restrict__ col, const int* __restrict__ row_start,
                           const int* __restrict__ cnt, const float* __restrict__ Hf,
                           const float* __restrict__ a_s, const float* __restrict__ a_d,
                           const float* __restrict__ bias, const float* __restrict__ gw,
                           const float* __restrict__ bw, float* __restrict__ outp, int N) {
    constexpr int M = HH * C;
    constexpr int FPL = (M + 63) / 64;
    int wid = blockIdx.x * (blockDim.x >> 6) + (threadIdx.x >> 6);
    int lane = threadIdx.x & 63;
    if (wid >= N) return;
    const int d = wid;
    const int start = row_start[d];
    const int deg = cnt[d];

    float adH[HH];
#pragma unroll
    for (int h = 0; h < HH; ++h) adH[h] = a_d[d * HH + h];

    float m[HH], s[HH];
#pragma unroll
    for (int h = 0; h < HH; ++h) { m[h] = -INFINITY; s[h] = 0.f; }
    for (int base = 0; base < deg; base += 64) {
        int j = base + lane;
        if (j < deg) {
            int src = col[start + j];
#pragma unroll
            for (int h = 0; h < HH; ++h) {
                float lg = a_s[src * HH + h] + adH[h];
                lg = (lg > 0.f) ? lg : NEG_SLOPE * lg;
                float nm = fmaxf(m[h], lg);
                s[h] = s[h] * __expf(m[h] - nm) + __expf(lg - nm);
                m[h] = nm;
            }
        }
    }
#pragma unroll
    for (int off = 32; off > 0; off >>= 1) {
#pragma unroll
        for (int h = 0; h < HH; ++h) {
            float om = __shfl_xor(m[h], off);
            float os = __shfl_xor(s[h], off);
            float nm = fmaxf(m[h], om);
            float t1 = (m[h] == -INFINITY) ? 0.f : s[h] * __expf(m[h] - nm);
            float t2 = (om == -INFINITY) ? 0.f : os * __expf(om - nm);
            m[h] = nm;
            s[h] = t1 + t2;
        }
    }

    const int t0 = lane * FPL;
    const bool active = (t0 < M);
    const int hl = active ? (t0 / C) : 0;
    const float mh = m[hl];
    const float invh = 1.f / (s[hl] + 1e-16f);
    const float adh = adH[hl];
    float acc[FPL] = {};
    for (int j = 0; j < deg; ++j) {
        int src = col[start + j];
        float lg = a_s[src * HH + hl] + adh;
        lg = (lg > 0.f) ? lg : NEG_SLOPE * lg;
        float coef = __expf(lg - mh) * invh;
        const float* hp = Hf + (size_t)src * M + t0;
        if constexpr (FPL == 2) {
            float2 hv = *reinterpret_cast<const float2*>(hp);
            acc[0] += coef * hv.x;
            acc[1] += coef * hv.y;
        } else {
            if (active) acc[0] += coef * hp[0];
        }
    }

    if constexpr (MODE == 0) {
        float v[FPL];
        float ls = 0.f;
#pragma unroll
        for (int jj = 0; jj < FPL; ++jj) {
            v[jj] = acc[jj] + bias[t0 + jj];
            ls += v[jj];
        }
#pragma unroll
        for (int off = 32; off > 0; off >>= 1) ls += __shfl_xor(ls, off);
        float mu = ls * (1.0f / M);
        float lv = 0.f;
#pragma unroll
        for (int jj = 0; jj < FPL; ++jj) {
            float dv = v[jj] - mu;
            lv += dv * dv;
        }
#pragma unroll
        for (int off = 32; off > 0; off >>= 1) lv += __shfl_xor(lv, off);
        float rstd = rsqrtf(lv * (1.0f / M) + LN_EPS);
#pragma unroll
        for (int jj = 0; jj < FPL; ++jj) {
            float y = (v[jj] - mu) * rstd * gw[t0 + jj] + bw[t0 + jj];
            v[jj] = (y > 0.f) ? y : expm1f(y);
        }
        if constexpr (FPL == 2) {
            *reinterpret_cast<float2*>(outp + (size_t)d * M + t0) = make_float2(v[0], v[1]);
        } else {
            outp[(size_t)d * M + t0] = v[0];
        }
    } else {
        float v = active ? (acc[0] + bias[t0]) : 0.f;
        float o = __shfl_xor(v, 1);
        if (active) {
            float mx = fmaxf(v, o);
            float l = mx + logf(expf(v - mx) + expf(o - mx));
            outp[(size_t)d * 2 + t0] = v - l;
        }
    }
}

extern "C" void kernel_launch(void* const* d_in, const int* in_sizes, int n_in,
                              void* d_out, int out_size, void* d_ws, size_t ws_size,
                              hipStream_t stream) {
    const float* x   = (const float*)d_in[0];
    const int*   ei  = (const int*)d_in[1];
    const float* W1  = (const float*)d_in[2];
    const float* as1 = (const float*)d_in[3];
    const float* ad1 = (const float*)d_in[4];
    const float* b1  = (const float*)d_in[5];
    const float* g1  = (const float*)d_in[6];
    const float* be1 = (const float*)d_in[7];
    const float* W2  = (const float*)d_in[8];
    const float* as2 = (const float*)d_in[9];
    const float* ad2 = (const float*)d_in[10];
    const float* b2  = (const float*)d_in[11];
    const float* g2  = (const float*)d_in[12];
    const float* be2 = (const float*)d_in[13];
    const float* W3  = (const float*)d_in[14];
    const float* as3 = (const float*)d_in[15];
    const float* ad3 = (const float*)d_in[16];
    const float* b3  = (const float*)d_in[17];

    int N = in_sizes[0] / 128;
    int E = in_sizes[1] / 2;
    int T = E + N;

    float* fbase = (float*)d_ws;
    float* h    = fbase;                          // N*128
    float* feat = h + (size_t)N * 128;            // N*128
    float* a_s  = feat + (size_t)N * 128;         // N*2
    float* a_d  = a_s + (size_t)N * 2;            // N*2
    int* cnt       = (int*)(a_d + (size_t)N * 2); // N
    int* partial   = cnt + N;                     // N
    int* bsum      = partial + N;                 // 512
    int* row_start = bsum + 512;                  // N
    int* cursor    = row_start + N;               // N
    int* col       = cursor + N;                  // E+N

    // ---- CSR build (dst-grouped, self-loops included) ----
    hipMemsetAsync(cnt, 0, (size_t)N * sizeof(int), stream);
    hist_kernel<<<(T + 255) / 256, 256, 0, stream>>>(ei, E, N, cnt);
    int nb = (N + 511) / 512;
    scan1_kernel<<<nb, 512, 0, stream>>>(cnt, partial, bsum, N);
    scan2_kernel<<<1, 512, 0, stream>>>(bsum, nb);
    scan3_kernel<<<(N + 255) / 256, 256, 0, stream>>>(partial, bsum, cnt, row_start, cursor, N);
    scatter_kernel<<<(T + 255) / 256, 256, 0, stream>>>(ei, E, N, cursor, col);

    int gblocks = (N + 3) / 4;
    int rblocks = (N + 63) / 64;

    // ---- layer 1: 128 -> (2 x 64), concat 128, LN+ELU ----
    gemm_tile<128, 128><<<rblocks, 256, 0, stream>>>(x, W1, h, N);
    att_red<2, 64><<<(2 * N + 3) / 4, 256, 0, stream>>>(h, as1, ad1, a_s, a_d, N);
    gat_gather<2, 64, 0><<<gblocks, 256, 0, stream>>>(col, row_start, cnt, h, a_s, a_d,
                                                      b1, g1, be1, feat, N);

    // ---- layer 2: 128 -> (2 x 32), concat 64, LN+ELU ----
    gemm_tile<128, 64><<<rblocks, 256, 0, stream>>>(feat, W2, h, N);
    att_red<2, 32><<<gblocks, 256, 0, stream>>>(h, as2, ad2, a_s, a_d, N);
    gat_gather<2, 32, 0><<<gblocks, 256, 0, stream>>>(col, row_start, cnt, h, a_s, a_d,
                                                      b2, g2, be2, feat, N);

    // ---- layer 3: 64 -> (1 x 2), bias + log_softmax ----
    l3_transform<<<(N + 255) / 256, 256, 0, stream>>>(feat, W3, as3, ad3, h, a_s, a_d, N);
    gat_gather<1, 2, 1><<<gblocks, 256, 0, stream>>>(col, row_start, cnt, h, a_s, a_d,
                                                     b3, nullptr, nullptr, (float*)d_out, N);
}

// Round 4
// 366.083 us; speedup vs baseline: 3.6032x; 1.2321x over previous
//
#include <hip/hip_runtime.h>
#include <hip/hip_fp16.h>
#include <math.h>

#define LN_EPS 1e-5f
#define NEG_SLOPE 0.2f

// ---------------- CSR build ----------------

__global__ void hist_kernel(const int* __restrict__ ei, int E, int N, int* __restrict__ cnt) {
    int e = blockIdx.x * blockDim.x + threadIdx.x;
    if (e >= E + N) return;
    int d = (e < E) ? ei[E + e] : (e - E);
    atomicAdd(&cnt[d], 1);
}

__global__ void scan1_kernel(const int* __restrict__ cnt, int* __restrict__ partial,
                             int* __restrict__ bsum, int N) {
    __shared__ int sh[512];
    int t = threadIdx.x;
    int i = blockIdx.x * 512 + t;
    int v = (i < N) ? cnt[i] : 0;
    sh[t] = v;
    __syncthreads();
    for (int off = 1; off < 512; off <<= 1) {
        int a = (t >= off) ? sh[t - off] : 0;
        __syncthreads();
        sh[t] += a;
        __syncthreads();
    }
    if (i < N) partial[i] = sh[t];
    if (t == 511) bsum[blockIdx.x] = sh[511];
}

__global__ void scan2_kernel(int* __restrict__ bsum, int nb) {
    __shared__ int sh[512];
    int t = threadIdx.x;
    int v = (t < nb) ? bsum[t] : 0;
    sh[t] = v;
    __syncthreads();
    for (int off = 1; off < 512; off <<= 1) {
        int a = (t >= off) ? sh[t - off] : 0;
        __syncthreads();
        sh[t] += a;
        __syncthreads();
    }
    if (t < nb) bsum[t] = sh[t] - v;
}

__global__ void scan3_kernel(const int* __restrict__ partial, const int* __restrict__ boff,
                             const int* __restrict__ cnt, int* __restrict__ row_start,
                             int* __restrict__ cursor, int N) {
    int i = blockIdx.x * blockDim.x + threadIdx.x;
    if (i >= N) return;
    int incl = partial[i] + boff[i >> 9];
    int st = incl - cnt[i];
    row_start[i] = st;
    cursor[i] = st;
}

__global__ void scatter_kernel(const int* __restrict__ ei, int E, int N,
                               int* __restrict__ cursor, int* __restrict__ col) {
    int e = blockIdx.x * blockDim.x + threadIdx.x;
    if (e >= E + N) return;
    int s = (e < E) ? ei[e] : (e - E);
    int d = (e < E) ? ei[E + e] : (e - E);
    int pos = atomicAdd(&cursor[d], 1);
    col[pos] = s;
}

// ---------------- register-tiled GEMM: Yh[N,M] = half(X[N,K] @ W[K,M]) ----------------
template <int K, int M>
__launch_bounds__(256)
__global__ void gemm_tile(const float* __restrict__ X, const float* __restrict__ W,
                          __half* __restrict__ Yh, int N) {
    constexpr int BR = 64, CT = 4, RT = 8, KC = 64;
    constexpr int TC = M / CT;
    constexpr int NT = TC * (BR / RT);
    __shared__ float Xs[BR][KC];
    __shared__ float Ws[KC][M];
    int tid = threadIdx.x;
    if (tid >= NT) return;
    int tc = tid % TC, tr = tid / TC;
    int row0 = blockIdx.x * BR;
    float acc[RT][CT] = {};
#pragma unroll
    for (int kc = 0; kc < K; kc += KC) {
        constexpr int XV = (BR * KC / 4) / NT;
#pragma unroll
        for (int i = 0; i < XV; ++i) {
            int f = tid + i * NT;
            int r = f / (KC / 4), c4 = f % (KC / 4);
            int row = row0 + r;
            float4 v = (row < N) ? *reinterpret_cast<const float4*>(&X[(size_t)row * K + kc + c4 * 4])
                                 : make_float4(0.f, 0.f, 0.f, 0.f);
            *reinterpret_cast<float4*>(&Xs[r][c4 * 4]) = v;
        }
        constexpr int WV = (KC * M / 4) / NT;
#pragma unroll
        for (int i = 0; i < WV; ++i) {
            int f = tid + i * NT;
            int kk = f / (M / 4), c4 = f % (M / 4);
            *reinterpret_cast<float4*>(&Ws[kk][c4 * 4]) =
                *reinterpret_cast<const float4*>(&W[(size_t)(kc + kk) * M + c4 * 4]);
        }
        __syncthreads();
#pragma unroll 4
        for (int k = 0; k < KC; ++k) {
            float4 wv = *reinterpret_cast<const float4*>(&Ws[k][tc * 4]);
#pragma unroll
            for (int rr = 0; rr < RT; ++rr) {
                float xv = Xs[tr * RT + rr][k];
                acc[rr][0] += xv * wv.x;
                acc[rr][1] += xv * wv.y;
                acc[rr][2] += xv * wv.z;
                acc[rr][3] += xv * wv.w;
            }
        }
        __syncthreads();
    }
#pragma unroll
    for (int rr = 0; rr < RT; ++rr) {
        int row = row0 + tr * RT + rr;
        if (row < N) {
            union { __half2 h[2]; uint2 u; } pk;
            pk.h[0] = __floats2half2_rn(acc[rr][0], acc[rr][1]);
            pk.h[1] = __floats2half2_rn(acc[rr][2], acc[rr][3]);
            *reinterpret_cast<uint2*>(&Yh[(size_t)row * M + tc * 4]) = pk.u;
        }
    }
}

// ---------------- attention logits from half h ----------------
template <int HH, int C>
__launch_bounds__(256)
__global__ void att_red(const __half* __restrict__ Hf, const float* __restrict__ AS,
                        const float* __restrict__ AD, float* __restrict__ a_s,
                        float* __restrict__ a_d, int N) {
    int wid = blockIdx.x * (blockDim.x >> 6) + (threadIdx.x >> 6);
    int lane = threadIdx.x & 63;
    if constexpr (C == 64) {
        int row = wid >> 1, head = wid & 1;
        if (row >= N) return;
        float v = __half2float(Hf[(size_t)row * 128 + head * 64 + lane]);
        float s1 = v * AS[head * 64 + lane];
        float s2 = v * AD[head * 64 + lane];
#pragma unroll
        for (int off = 32; off > 0; off >>= 1) {
            s1 += __shfl_xor(s1, off);
            s2 += __shfl_xor(s2, off);
        }
        if (lane == 0) {
            a_s[row * 2 + head] = s1;
            a_d[row * 2 + head] = s2;
        }
    } else {
        int row = wid;
        if (row >= N) return;
        float v = __half2float(Hf[(size_t)row * 64 + lane]);
        float s1 = v * AS[lane];
        float s2 = v * AD[lane];
#pragma unroll
        for (int off = 16; off > 0; off >>= 1) {
            s1 += __shfl_xor(s1, off);
            s2 += __shfl_xor(s2, off);
        }
        if ((lane & 31) == 0) {
            a_s[row * 2 + (lane >> 5)] = s1;
            a_d[row * 2 + (lane >> 5)] = s2;
        }
    }
}

// ---------------- layer 3 transform ----------------
__launch_bounds__(256)
__global__ void l3_transform(const float* __restrict__ X, const float* __restrict__ W3,
                             const float* __restrict__ as3, const float* __restrict__ ad3,
                             __half* __restrict__ h3h, float* __restrict__ a_s,
                             float* __restrict__ a_d, int N) {
    int n = blockIdx.x * blockDim.x + threadIdx.x;
    if (n >= N) return;
    const float4* xp = reinterpret_cast<const float4*>(&X[(size_t)n * 64]);
    float h0 = 0.f, h1 = 0.f;
#pragma unroll
    for (int i = 0; i < 16; ++i) {
        float4 x4 = xp[i];
        int k = i * 4;
        h0 += x4.x * W3[(k + 0) * 2] + x4.y * W3[(k + 1) * 2] +
              x4.z * W3[(k + 2) * 2] + x4.w * W3[(k + 3) * 2];
        h1 += x4.x * W3[(k + 0) * 2 + 1] + x4.y * W3[(k + 1) * 2 + 1] +
              x4.z * W3[(k + 2) * 2 + 1] + x4.w * W3[(k + 3) * 2 + 1];
    }
    *reinterpret_cast<__half2*>(&h3h[(size_t)n * 2]) = __floats2half2_rn(h0, h1);
    a_s[n] = h0 * as3[0] + h1 * as3[1];
    a_d[n] = h0 * ad3[0] + h1 * ad3[1];
}

// ---------------- fused GAT aggregation: one wave per dst node ----------------
// deg<=64 fast path: edge j owned by lane j; logits/exps in registers, shfl-broadcast.
template <int HH, int C, int MODE>
__launch_bounds__(256)
__global__ void gat_gather(const int* __restrict__ col, const int* __restrict__ row_start,
                           const int* __restrict__ cnt, const __half* __restrict__ Hf,
                           const float* __restrict__ a_s, const float* __restrict__ a_d,
                           const float* __restrict__ bias, const float* __restrict__ gw,
                           const float* __restrict__ bw, float* __restrict__ outp, int N) {
    constexpr int M = HH * C;
    constexpr int FPL = (M + 63) / 64;
    int wid = blockIdx.x * (blockDim.x >> 6) + (threadIdx.x >> 6);
    int lane = threadIdx.x & 63;
    if (wid >= N) return;
    const int d = wid;
    const int start = row_start[d];
    const int deg = cnt[d];

    float ad0 = a_d[d * HH];
    float ad1 = (HH == 2) ? a_d[d * HH + 1] : 0.f;

    const int t0 = lane * FPL;
    const bool active = (t0 < M);
    const int hl = (HH == 2 && active) ? (t0 / C) : 0;

    float m0 = -INFINITY, m1 = -INFINITY, s0 = 0.f, s1 = 0.f;
    float acc[FPL] = {};

    if (deg <= 64) {
        int src_l = (lane < deg) ? col[start + lane] : 0;
        float lg0 = -INFINITY, lg1 = -INFINITY;
        if (lane < deg) {
            float v0 = a_s[src_l * HH] + ad0;
            lg0 = (v0 > 0.f) ? v0 : NEG_SLOPE * v0;
            if (HH == 2) {
                float v1 = a_s[src_l * HH + 1] + ad1;
                lg1 = (v1 > 0.f) ? v1 : NEG_SLOPE * v1;
            }
        }
        m0 = lg0;
        m1 = lg1;
#pragma unroll
        for (int off = 32; off > 0; off >>= 1) {
            m0 = fmaxf(m0, __shfl_xor(m0, off));
            if (HH == 2) m1 = fmaxf(m1, __shfl_xor(m1, off));
        }
        float e0 = (lane < deg) ? __expf(lg0 - m0) : 0.f;
        float e1 = (HH == 2 && lane < deg) ? __expf(lg1 - m1) : 0.f;
        s0 = e0;
        s1 = e1;
#pragma unroll
        for (int off = 32; off > 0; off >>= 1) {
            s0 += __shfl_xor(s0, off);
            if (HH == 2) s1 += __shfl_xor(s1, off);
        }
        // phase 2: unnormalized accumulate, normalize once at the end
        for (int j = 0; j < deg; ++j) {
            int src = __shfl(src_l, j);
            float coef;
            if constexpr (HH == 2) {
                float c0 = __shfl(e0, j);
                float c1 = __shfl(e1, j);
                coef = (hl == 0) ? c0 : c1;
            } else {
                coef = __shfl(e0, j);
            }
            const __half* hp = Hf + (size_t)src * M + t0;
            if constexpr (FPL == 2) {
                float2 f = __half22float2(*reinterpret_cast<const __half2*>(hp));
                acc[0] += coef * f.x;
                acc[1] += coef * f.y;
            } else {
                if (active) acc[0] += coef * __half2float(*hp);
            }
        }
    } else {
        // rare fallback: online softmax + per-edge recompute
        for (int base = 0; base < deg; base += 64) {
            int j = base + lane;
            if (j < deg) {
                int src = col[start + j];
                float v0 = a_s[src * HH] + ad0;
                v0 = (v0 > 0.f) ? v0 : NEG_SLOPE * v0;
                float nm = fmaxf(m0, v0);
                s0 = s0 * __expf(m0 - nm) + __expf(v0 - nm);
                m0 = nm;
                if (HH == 2) {
                    float v1 = a_s[src * HH + 1] + ad1;
                    v1 = (v1 > 0.f) ? v1 : NEG_SLOPE * v1;
                    float nm1 = fmaxf(m1, v1);
                    s1 = s1 * __expf(m1 - nm1) + __expf(v1 - nm1);
                    m1 = nm1;
                }
            }
        }
#pragma unroll
        for (int off = 32; off > 0; off >>= 1) {
            float om = __shfl_xor(m0, off);
            float os = __shfl_xor(s0, off);
            float nm = fmaxf(m0, om);
            float t1 = (m0 == -INFINITY) ? 0.f : s0 * __expf(m0 - nm);
            float t2 = (om == -INFINITY) ? 0.f : os * __expf(om - nm);
            m0 = nm;
            s0 = t1 + t2;
            if (HH == 2) {
                float om1 = __shfl_xor(m1, off);
                float os1 = __shfl_xor(s1, off);
                float nm1 = fmaxf(m1, om1);
                float u1 = (m1 == -INFINITY) ? 0.f : s1 * __expf(m1 - nm1);
                float u2 = (om1 == -INFINITY) ? 0.f : os1 * __expf(om1 - nm1);
                m1 = nm1;
                s1 = u1 + u2;
            }
        }
        float mh = (hl == 0) ? m0 : m1;
        float adh = (hl == 0) ? ad0 : ad1;
        for (int j = 0; j < deg; ++j) {
            int src = col[start + j];
            float v = a_s[src * HH + hl] + adh;
            v = (v > 0.f) ? v : NEG_SLOPE * v;
            float coef = __expf(v - mh);
            const __half* hp = Hf + (size_t)src * M + t0;
            if constexpr (FPL == 2) {
                float2 f = __half22float2(*reinterpret_cast<const __half2*>(hp));
                acc[0] += coef * f.x;
                acc[1] += coef * f.y;
            } else {
                if (active) acc[0] += coef * __half2float(*hp);
            }
        }
    }

    float sh = (hl == 0) ? s0 : s1;
    float inv = 1.f / (sh + 1e-16f);
#pragma unroll
    for (int jj = 0; jj < FPL; ++jj) acc[jj] *= inv;

    if constexpr (MODE == 0) {
        float v[FPL];
        float ls = 0.f;
#pragma unroll
        for (int jj = 0; jj < FPL; ++jj) {
            v[jj] = acc[jj] + bias[t0 + jj];
            ls += v[jj];
        }
#pragma unroll
        for (int off = 32; off > 0; off >>= 1) ls += __shfl_xor(ls, off);
        float mu = ls * (1.0f / M);
        float lv = 0.f;
#pragma unroll
        for (int jj = 0; jj < FPL; ++jj) {
            float dv = v[jj] - mu;
            lv += dv * dv;
        }
#pragma unroll
        for (int off = 32; off > 0; off >>= 1) lv += __shfl_xor(lv, off);
        float rstd = rsqrtf(lv * (1.0f / M) + LN_EPS);
#pragma unroll
        for (int jj = 0; jj < FPL; ++jj) {
            float y = (v[jj] - mu) * rstd * gw[t0 + jj] + bw[t0 + jj];
            v[jj] = (y > 0.f) ? y : expm1f(y);
        }
        if constexpr (FPL == 2) {
            *reinterpret_cast<float2*>(outp + (size_t)d * M + t0) = make_float2(v[0], v[1]);
        } else {
            outp[(size_t)d * M + t0] = v[0];
        }
    } else {
        float v = active ? (acc[0] + bias[t0]) : 0.f;
        float o = __shfl_xor(v, 1);
        if (active) {
            float mx = fmaxf(v, o);
            float l = mx + logf(expf(v - mx) + expf(o - mx));
            outp[(size_t)d * 2 + t0] = v - l;
        }
    }
}

extern "C" void kernel_launch(void* const* d_in, const int* in_sizes, int n_in,
                              void* d_out, int out_size, void* d_ws, size_t ws_size,
                              hipStream_t stream) {
    const float* x   = (const float*)d_in[0];
    const int*   ei  = (const int*)d_in[1];
    const float* W1  = (const float*)d_in[2];
    const float* as1 = (const float*)d_in[3];
    const float* ad1 = (const float*)d_in[4];
    const float* b1  = (const float*)d_in[5];
    const float* g1  = (const float*)d_in[6];
    const float* be1 = (const float*)d_in[7];
    const float* W2  = (const float*)d_in[8];
    const float* as2 = (const float*)d_in[9];
    const float* ad2 = (const float*)d_in[10];
    const float* b2  = (const float*)d_in[11];
    const float* g2  = (const float*)d_in[12];
    const float* be2 = (const float*)d_in[13];
    const float* W3  = (const float*)d_in[14];
    const float* as3 = (const float*)d_in[15];
    const float* ad3 = (const float*)d_in[16];
    const float* b3  = (const float*)d_in[17];

    int N = in_sizes[0] / 128;
    int E = in_sizes[1] / 2;
    int T = E + N;

    __half* Hh  = (__half*)d_ws;                         // N*128 halfs
    float* feat = (float*)(Hh + (size_t)N * 128);        // N*128 f32
    float* a_s  = feat + (size_t)N * 128;                // N*2
    float* a_d  = a_s + (size_t)N * 2;                   // N*2
    int* cnt       = (int*)(a_d + (size_t)N * 2);        // N
    int* partial   = cnt + N;                            // N
    int* bsum      = partial + N;                        // 512
    int* row_start = bsum + 512;                         // N
    int* cursor    = row_start + N;                      // N
    int* col       = cursor + N;                         // E+N

    // ---- CSR build (dst-grouped, self-loops included) ----
    hipMemsetAsync(cnt, 0, (size_t)N * sizeof(int), stream);
    hist_kernel<<<(T + 255) / 256, 256, 0, stream>>>(ei, E, N, cnt);
    int nb = (N + 511) / 512;
    scan1_kernel<<<nb, 512, 0, stream>>>(cnt, partial, bsum, N);
    scan2_kernel<<<1, 512, 0, stream>>>(bsum, nb);
    scan3_kernel<<<(N + 255) / 256, 256, 0, stream>>>(partial, bsum, cnt, row_start, cursor, N);
    scatter_kernel<<<(T + 255) / 256, 256, 0, stream>>>(ei, E, N, cursor, col);

    int gblocks = (N + 3) / 4;
    int rblocks = (N + 63) / 64;

    // ---- layer 1: 128 -> (2 x 64), concat 128, LN+ELU ----
    gemm_tile<128, 128><<<rblocks, 256, 0, stream>>>(x, W1, Hh, N);
    att_red<2, 64><<<(2 * N + 3) / 4, 256, 0, stream>>>(Hh, as1, ad1, a_s, a_d, N);
    gat_gather<2, 64, 0><<<gblocks, 256, 0, stream>>>(col, row_start, cnt, Hh, a_s, a_d,
                                                      b1, g1, be1, feat, N);

    // ---- layer 2: 128 -> (2 x 32), concat 64, LN+ELU ----
    gemm_tile<128, 64><<<rblocks, 128, 0, stream>>>(feat, W2, Hh, N);
    att_red<2, 32><<<gblocks, 256, 0, stream>>>(Hh, as2, ad2, a_s, a_d, N);
    gat_gather<2, 32, 0><<<gblocks, 256, 0, stream>>>(col, row_start, cnt, Hh, a_s, a_d,
                                                      b2, g2, be2, feat, N);

    // ---- layer 3: 64 -> (1 x 2), bias + log_softmax ----
    l3_transform<<<(N + 255) / 256, 256, 0, stream>>>(feat, W3, as3, ad3, Hh, a_s, a_d, N);
    gat_gather<1, 2, 1><<<gblocks, 256, 0, stream>>>(col, row_start, cnt, Hh, a_s, a_d,
                                                     b3, nullptr, nullptr, (float*)d_out, N);
}

// Round 6
// 360.777 us; speedup vs baseline: 3.6562x; 1.0147x over previous
//
#include <hip/hip_runtime.h>
#include <hip/hip_fp16.h>
#include <math.h>

#define LN_EPS 1e-5f
#define NEG_SLOPE 0.2f

// ---------------- CSR build ----------------

__global__ void hist_kernel(const int* __restrict__ ei, int E, int N, int* __restrict__ cnt) {
    int e = blockIdx.x * blockDim.x + threadIdx.x;
    if (e >= E + N) return;
    int d = (e < E) ? ei[E + e] : (e - E);
    atomicAdd(&cnt[d], 1);
}

__global__ void scan1_kernel(const int* __restrict__ cnt, int* __restrict__ partial,
                             int* __restrict__ bsum, int N) {
    __shared__ int sh[512];
    int t = threadIdx.x;
    int i = blockIdx.x * 512 + t;
    int v = (i < N) ? cnt[i] : 0;
    sh[t] = v;
    __syncthreads();
    for (int off = 1; off < 512; off <<= 1) {
        int a = (t >= off) ? sh[t - off] : 0;
        __syncthreads();
        sh[t] += a;
        __syncthreads();
    }
    if (i < N) partial[i] = sh[t];
    if (t == 511) bsum[blockIdx.x] = sh[511];
}

__global__ void scan2_kernel(int* __restrict__ bsum, int nb) {
    __shared__ int sh[512];
    int t = threadIdx.x;
    int v = (t < nb) ? bsum[t] : 0;
    sh[t] = v;
    __syncthreads();
    for (int off = 1; off < 512; off <<= 1) {
        int a = (t >= off) ? sh[t - off] : 0;
        __syncthreads();
        sh[t] += a;
        __syncthreads();
    }
    if (t < nb) bsum[t] = sh[t] - v;
}

__global__ void scan3_kernel(const int* __restrict__ partial, const int* __restrict__ boff,
                             const int* __restrict__ cnt, int* __restrict__ row_start,
                             int* __restrict__ cursor, int N) {
    int i = blockIdx.x * blockDim.x + threadIdx.x;
    if (i >= N) return;
    int incl = partial[i] + boff[i >> 9];
    int st = incl - cnt[i];
    row_start[i] = st;
    cursor[i] = st;
}

__global__ void scatter_kernel(const int* __restrict__ ei, int E, int N,
                               int* __restrict__ cursor, int* __restrict__ col) {
    int e = blockIdx.x * blockDim.x + threadIdx.x;
    if (e >= E + N) return;
    int s = (e < E) ? ei[e] : (e - E);
    int d = (e < E) ? ei[E + e] : (e - E);
    int pos = atomicAdd(&cursor[d], 1);
    col[pos] = s;
}

// ---------------- register-tiled GEMM: Yh[N,M] = half(X[N,K] @ W[K,M]) ----------------
template <int K, int M>
__launch_bounds__(256)
__global__ void gemm_tile(const float* __restrict__ X, const float* __restrict__ W,
                          __half* __restrict__ Yh, int N) {
    constexpr int BR = 64, CT = 4, RT = 8, KC = 64;
    constexpr int TC = M / CT;
    constexpr int NT = TC * (BR / RT);
    __shared__ float Xs[BR][KC];
    __shared__ float Ws[KC][M];
    int tid = threadIdx.x;
    if (tid >= NT) return;
    int tc = tid % TC, tr = tid / TC;
    int row0 = blockIdx.x * BR;
    float acc[RT][CT] = {};
#pragma unroll
    for (int kc = 0; kc < K; kc += KC) {
        constexpr int XV = (BR * KC / 4) / NT;
#pragma unroll
        for (int i = 0; i < XV; ++i) {
            int f = tid + i * NT;
            int r = f / (KC / 4), c4 = f % (KC / 4);
            int row = row0 + r;
            float4 v = (row < N) ? *reinterpret_cast<const float4*>(&X[(size_t)row * K + kc + c4 * 4])
                                 : make_float4(0.f, 0.f, 0.f, 0.f);
            *reinterpret_cast<float4*>(&Xs[r][c4 * 4]) = v;
        }
        constexpr int WV = (KC * M / 4) / NT;
#pragma unroll
        for (int i = 0; i < WV; ++i) {
            int f = tid + i * NT;
            int kk = f / (M / 4), c4 = f % (M / 4);
            *reinterpret_cast<float4*>(&Ws[kk][c4 * 4]) =
                *reinterpret_cast<const float4*>(&W[(size_t)(kc + kk) * M + c4 * 4]);
        }
        __syncthreads();
#pragma unroll 4
        for (int k = 0; k < KC; ++k) {
            float4 wv = *reinterpret_cast<const float4*>(&Ws[k][tc * 4]);
#pragma unroll
            for (int rr = 0; rr < RT; ++rr) {
                float xv = Xs[tr * RT + rr][k];
                acc[rr][0] += xv * wv.x;
                acc[rr][1] += xv * wv.y;
                acc[rr][2] += xv * wv.z;
                acc[rr][3] += xv * wv.w;
            }
        }
        __syncthreads();
    }
#pragma unroll
    for (int rr = 0; rr < RT; ++rr) {
        int row = row0 + tr * RT + rr;
        if (row < N) {
            union { __half2 h[2]; uint2 u; } pk;
            pk.h[0] = __floats2half2_rn(acc[rr][0], acc[rr][1]);
            pk.h[1] = __floats2half2_rn(acc[rr][2], acc[rr][3]);
            *reinterpret_cast<uint2*>(&Yh[(size_t)row * M + tc * 4]) = pk.u;
        }
    }
}

// ---------------- attention logits from half h ----------------
template <int HH, int C>
__launch_bounds__(256)
__global__ void att_red(const __half* __restrict__ Hf, const float* __restrict__ AS,
                        const float* __restrict__ AD, float* __restrict__ a_s,
                        float* __restrict__ a_d, int N) {
    int wid = blockIdx.x * (blockDim.x >> 6) + (threadIdx.x >> 6);
    int lane = threadIdx.x & 63;
    if constexpr (C == 64) {
        int row = wid >> 1, head = wid & 1;
        if (row >= N) return;
        float v = __half2float(Hf[(size_t)row * 128 + head * 64 + lane]);
        float s1 = v * AS[head * 64 + lane];
        float s2 = v * AD[head * 64 + lane];
#pragma unroll
        for (int off = 32; off > 0; off >>= 1) {
            s1 += __shfl_xor(s1, off);
            s2 += __shfl_xor(s2, off);
        }
        if (lane == 0) {
            a_s[row * 2 + head] = s1;
            a_d[row * 2 + head] = s2;
        }
    } else {
        int row = wid;
        if (row >= N) return;
        float v = __half2float(Hf[(size_t)row * 64 + lane]);
        float s1 = v * AS[lane];
        float s2 = v * AD[lane];
#pragma unroll
        for (int off = 16; off > 0; off >>= 1) {
            s1 += __shfl_xor(s1, off);
            s2 += __shfl_xor(s2, off);
        }
        if ((lane & 31) == 0) {
            a_s[row * 2 + (lane >> 5)] = s1;
            a_d[row * 2 + (lane >> 5)] = s2;
        }
    }
}

// ---------------- layer 3 transform ----------------
__launch_bounds__(256)
__global__ void l3_transform(const float* __restrict__ X, const float* __restrict__ W3,
                             const float* __restrict__ as3, const float* __restrict__ ad3,
                             __half* __restrict__ h3h, float* __restrict__ a_s,
                             float* __restrict__ a_d, int N) {
    int n = blockIdx.x * blockDim.x + threadIdx.x;
    if (n >= N) return;
    const float4* xp = reinterpret_cast<const float4*>(&X[(size_t)n * 64]);
    float h0 = 0.f, h1 = 0.f;
#pragma unroll
    for (int i = 0; i < 16; ++i) {
        float4 x4 = xp[i];
        int k = i * 4;
        h0 += x4.x * W3[(k + 0) * 2] + x4.y * W3[(k + 1) * 2] +
              x4.z * W3[(k + 2) * 2] + x4.w * W3[(k + 3) * 2];
        h1 += x4.x * W3[(k + 0) * 2 + 1] + x4.y * W3[(k + 1) * 2 + 1] +
              x4.z * W3[(k + 2) * 2 + 1] + x4.w * W3[(k + 3) * 2 + 1];
    }
    *reinterpret_cast<__half2*>(&h3h[(size_t)n * 2]) = __floats2half2_rn(h0, h1);
    a_s[n] = h0 * as3[0] + h1 * as3[1];
    a_d[n] = h0 * ad3[0] + h1 * ad3[1];
}

// accumulate one row segment: acc[VE] += coef * Hf_row[fl*VE .. fl*VE+VE)
template <int VE>
__device__ inline void row_fma(const __half* __restrict__ hp, float coef, float* acc) {
    if constexpr (VE == 8) {
        union { uint4 u; __half2 h[4]; } pk;
        pk.u = *reinterpret_cast<const uint4*>(hp);
#pragma unroll
        for (int i = 0; i < 4; ++i) {
            float2 f = __half22float2(pk.h[i]);
            acc[2 * i] += coef * f.x;
            acc[2 * i + 1] += coef * f.y;
        }
    } else {
        union { uint2 u; __half2 h[2]; } pk;
        pk.u = *reinterpret_cast<const uint2*>(hp);
#pragma unroll
        for (int i = 0; i < 2; ++i) {
            float2 f = __half22float2(pk.h[i]);
            acc[2 * i] += coef * f.x;
            acc[2 * i + 1] += coef * f.y;
        }
    }
}

// ---------------- fused GAT aggregation: one wave per dst node ----------------
// MODE 0 (M=128/64, HH=2): lanes own edges for softmax; 4 16-lane groups each
//   fetch a full row (16B/lane) -> 4 edges in flight; group partials shfl-summed.
// MODE 1 (M=2): lane-per-edge, everything in-lane, one shfl-tree reduce.
template <int HH, int C, int MODE>
__launch_bounds__(256)
__global__ void gat_gather(const int* __restrict__ col, const int* __restrict__ row_start,
                           const int* __restrict__ cnt, const __half* __restrict__ Hf,
                           const float* __restrict__ a_s, const float* __restrict__ a_d,
                           const float* __restrict__ bias, const float* __restrict__ gw,
                           const float* __restrict__ bw, float* __restrict__ outp, int N) {
    int wid = blockIdx.x * (blockDim.x >> 6) + (threadIdx.x >> 6);
    int lane = threadIdx.x & 63;
    if (wid >= N) return;
    const int d = wid;
    const int start = row_start[d];
    const int deg = cnt[d];

    if constexpr (MODE == 1) {
        float ad0 = a_d[d];
        float m0 = -INFINITY, s0 = 0.f, acc0 = 0.f, acc1 = 0.f;
        if (deg <= 64) {
            int src_l = (lane < deg) ? col[start + lane] : 0;
            float lg0 = -INFINITY;
            if (lane < deg) {
                float v0 = a_s[src_l] + ad0;
                lg0 = (v0 > 0.f) ? v0 : NEG_SLOPE * v0;
            }
            m0 = lg0;
#pragma unroll
            for (int off = 32; off > 0; off >>= 1) m0 = fmaxf(m0, __shfl_xor(m0, off));
            float e0 = 0.f;
            if (lane < deg) {
                e0 = __expf(lg0 - m0);
                float2 f = __half22float2(*reinterpret_cast<const __half2*>(Hf + (size_t)src_l * 2));
                acc0 = e0 * f.x;
                acc1 = e0 * f.y;
            }
            s0 = e0;
#pragma unroll
            for (int off = 32; off > 0; off >>= 1) {
                s0 += __shfl_xor(s0, off);
                acc0 += __shfl_xor(acc0, off);
                acc1 += __shfl_xor(acc1, off);
            }
        } else {
            for (int base = 0; base < deg; base += 64) {
                int j = base + lane;
                if (j < deg) {
                    int src = col[start + j];
                    float v0 = a_s[src] + ad0;
                    v0 = (v0 > 0.f) ? v0 : NEG_SLOPE * v0;
                    float nm = fmaxf(m0, v0);
                    float sc = (m0 == -INFINITY) ? 0.f : __expf(m0 - nm);
                    float e = __expf(v0 - nm);
                    float2 f = __half22float2(*reinterpret_cast<const __half2*>(Hf + (size_t)src * 2));
                    s0 = s0 * sc + e;
                    acc0 = acc0 * sc + e * f.x;
                    acc1 = acc1 * sc + e * f.y;
                    m0 = nm;
                }
            }
#pragma unroll
            for (int off = 32; off > 0; off >>= 1) {
                float om = __shfl_xor(m0, off);
                float os = __shfl_xor(s0, off);
                float oa0 = __shfl_xor(acc0, off);
                float oa1 = __shfl_xor(acc1, off);
                float nm = fmaxf(m0, om);
                float t1 = (m0 == -INFINITY) ? 0.f : __expf(m0 - nm);
                float t2 = (om == -INFINITY) ? 0.f : __expf(om - nm);
                m0 = nm;
                s0 = s0 * t1 + os * t2;
                acc0 = acc0 * t1 + oa0 * t2;
                acc1 = acc1 * t1 + oa1 * t2;
            }
        }
        if (lane == 0) {
            float inv = 1.f / (s0 + 1e-16f);
            float h0 = acc0 * inv + bias[0];
            float h1 = acc1 * inv + bias[1];
            float mx = fmaxf(h0, h1);
            float l = mx + logf(expf(h0 - mx) + expf(h1 - mx));
            *reinterpret_cast<float2*>(outp + (size_t)d * 2) = make_float2(h0 - l, h1 - l);
        }
    }

    if constexpr (MODE == 0) {
        constexpr int M = HH * C;
        constexpr int VE = (M / 16 > 0) ? (M / 16) : 1;  // 8 (M=128) or 4 (M=64)
        const int g = lane >> 4;            // group id: which edge in the 4-batch
        const int fl = lane & 15;           // lane within group: feature segment
        const int hl = fl >> 3;             // head of this lane's features

        float ad0 = a_d[d * 2];
        float ad1 = a_d[d * 2 + 1];

        float m0 = -INFINITY, m1 = -INFINITY, s0 = 0.f, s1 = 0.f;
        float acc[VE] = {};

        if (deg <= 64) {
            int src_l = (lane < deg) ? col[start + lane] : 0;
            float lg0 = -INFINITY, lg1 = -INFINITY;
            if (lane < deg) {
                float2 av = *reinterpret_cast<const float2*>(a_s + (size_t)src_l * 2);
                float v0 = av.x + ad0;
                lg0 = (v0 > 0.f) ? v0 : NEG_SLOPE * v0;
                float v1 = av.y + ad1;
                lg1 = (v1 > 0.f) ? v1 : NEG_SLOPE * v1;
            }
            m0 = lg0;
            m1 = lg1;
#pragma unroll
            for (int off = 32; off > 0; off >>= 1) {
                m0 = fmaxf(m0, __shfl_xor(m0, off));
                m1 = fmaxf(m1, __shfl_xor(m1, off));
            }
            float e0 = (lane < deg) ? __expf(lg0 - m0) : 0.f;
            float e1 = (lane < deg) ? __expf(lg1 - m1) : 0.f;
            s0 = e0;
            s1 = e1;
#pragma unroll
            for (int off = 32; off > 0; off >>= 1) {
                s0 += __shfl_xor(s0, off);
                s1 += __shfl_xor(s1, off);
            }
            for (int j0 = 0; j0 < deg; j0 += 4) {
                int j = j0 + g;
                bool ok = (j < deg);
                int jc = ok ? j : 0;
                int src = __shfl(src_l, jc);
                float c0 = __shfl(e0, jc);
                float c1 = __shfl(e1, jc);
                float coef = (hl == 0) ? c0 : c1;
                if (!ok) coef = 0.f;
                row_fma<VE>(Hf + (size_t)src * M + fl * VE, coef, acc);
            }
        } else {
            for (int base = 0; base < deg; base += 64) {
                int j = base + lane;
                if (j < deg) {
                    int src = col[start + j];
                    float2 av = *reinterpret_cast<const float2*>(a_s + (size_t)src * 2);
                    float v0 = av.x + ad0;
                    v0 = (v0 > 0.f) ? v0 : NEG_SLOPE * v0;
                    float nm = fmaxf(m0, v0);
                    s0 = s0 * ((m0 == -INFINITY) ? 0.f : __expf(m0 - nm)) + __expf(v0 - nm);
                    m0 = nm;
                    float v1 = av.y + ad1;
                    v1 = (v1 > 0.f) ? v1 : NEG_SLOPE * v1;
                    float nm1 = fmaxf(m1, v1);
                    s1 = s1 * ((m1 == -INFINITY) ? 0.f : __expf(m1 - nm1)) + __expf(v1 - nm1);
                    m1 = nm1;
                }
            }
#pragma unroll
            for (int off = 32; off > 0; off >>= 1) {
                float om = __shfl_xor(m0, off);
                float os = __shfl_xor(s0, off);
                float nm = fmaxf(m0, om);
                float t1 = (m0 == -INFINITY) ? 0.f : __expf(m0 - nm);
                float t2 = (om == -INFINITY) ? 0.f : __expf(om - nm);
                m0 = nm;
                s0 = s0 * t1 + os * t2;
                float om1 = __shfl_xor(m1, off);
                float os1 = __shfl_xor(s1, off);
                float nm1 = fmaxf(m1, om1);
                float u1 = (m1 == -INFINITY) ? 0.f : __expf(m1 - nm1);
                float u2 = (om1 == -INFINITY) ? 0.f : __expf(om1 - nm1);
                m1 = nm1;
                s1 = s1 * u1 + os1 * u2;
            }
            float mh = (hl == 0) ? m0 : m1;
            float adh = (hl == 0) ? ad0 : ad1;
            for (int j0 = 0; j0 < deg; j0 += 4) {
                int j = j0 + g;
                bool ok = (j < deg);
                int jc = ok ? j : 0;
                int src = col[start + jc];
                float v = a_s[(size_t)src * 2 + hl] + adh;
                v = (v > 0.f) ? v : NEG_SLOPE * v;
                float coef = ok ? __expf(v - mh) : 0.f;
                row_fma<VE>(Hf + (size_t)src * M + fl * VE, coef, acc);
            }
        }

        // sum partials across the 4 groups
#pragma unroll
        for (int jj = 0; jj < VE; ++jj) {
            acc[jj] += __shfl_xor(acc[jj], 16);
            acc[jj] += __shfl_xor(acc[jj], 32);
        }
        float inv = 1.f / (((hl == 0) ? s0 : s1) + 1e-16f);

        // bias + LayerNorm + ELU in 16-lane x VE layout
        float v[VE];
        float ls = 0.f;
#pragma unroll
        for (int jj = 0; jj < VE; ++jj) {
            v[jj] = acc[jj] * inv + bias[fl * VE + jj];
            ls += v[jj];
        }
#pragma unroll
        for (int off = 8; off > 0; off >>= 1) ls += __shfl_xor(ls, off);
        float mu = ls * (1.0f / M);
        float lv = 0.f;
#pragma unroll
        for (int jj = 0; jj < VE; ++jj) {
            float dv = v[jj] - mu;
            lv += dv * dv;
        }
#pragma unroll
        for (int off = 8; off > 0; off >>= 1) lv += __shfl_xor(lv, off);
        float rstd = rsqrtf(lv * (1.0f / M) + LN_EPS);
#pragma unroll
        for (int jj = 0; jj < VE; ++jj) {
            float y = (v[jj] - mu) * rstd * gw[fl * VE + jj] + bw[fl * VE + jj];
            v[jj] = (y > 0.f) ? y : expm1f(y);
        }
        if (g == 0) {
            float* op = outp + (size_t)d * M + fl * VE;
#pragma unroll
            for (int q = 0; q < VE / 4; ++q) {
                *reinterpret_cast<float4*>(op + q * 4) =
                    make_float4(v[q * 4 + 0], v[q * 4 + 1], v[q * 4 + 2], v[q * 4 + 3]);
            }
        }
    }
}

extern "C" void kernel_launch(void* const* d_in, const int* in_sizes, int n_in,
                              void* d_out, int out_size, void* d_ws, size_t ws_size,
                              hipStream_t stream) {
    const float* x   = (const float*)d_in[0];
    const int*   ei  = (const int*)d_in[1];
    const float* W1  = (const float*)d_in[2];
    const float* as1 = (const float*)d_in[3];
    const float* ad1 = (const float*)d_in[4];
    const float* b1  = (const float*)d_in[5];
    const float* g1  = (const float*)d_in[6];
    const float* be1 = (const float*)d_in[7];
    const float* W2  = (const float*)d_in[8];
    const float* as2 = (const float*)d_in[9];
    const float* ad2 = (const float*)d_in[10];
    const float* b2  = (const float*)d_in[11];
    const float* g2  = (const float*)d_in[12];
    const float* be2 = (const float*)d_in[13];
    const float* W3  = (const float*)d_in[14];
    const float* as3 = (const float*)d_in[15];
    const float* ad3 = (const float*)d_in[16];
    const float* b3  = (const float*)d_in[17];

    int N = in_sizes[0] / 128;
    int E = in_sizes[1] / 2;
    int T = E + N;

    __half* Hh  = (__half*)d_ws;                         // N*128 halfs
    float* feat = (float*)(Hh + (size_t)N * 128);        // N*128 f32
    float* a_s  = feat + (size_t)N * 128;                // N*2
    float* a_d  = a_s + (size_t)N * 2;                   // N*2
    int* cnt       = (int*)(a_d + (size_t)N * 2);        // N
    int* partial   = cnt + N;                            // N
    int* bsum      = partial + N;                        // 512
    int* row_start = bsum + 512;                         // N
    int* cursor    = row_start + N;                      // N
    int* col       = cursor + N;                         // E+N

    // ---- CSR build (dst-grouped, self-loops included) ----
    (void)hipMemsetAsync(cnt, 0, (size_t)N * sizeof(int), stream);
    hist_kernel<<<(T + 255) / 256, 256, 0, stream>>>(ei, E, N, cnt);
    int nb = (N + 511) / 512;
    scan1_kernel<<<nb, 512, 0, stream>>>(cnt, partial, bsum, N);
    scan2_kernel<<<1, 512, 0, stream>>>(bsum, nb);
    scan3_kernel<<<(N + 255) / 256, 256, 0, stream>>>(partial, bsum, cnt, row_start, cursor, N);
    scatter_kernel<<<(T + 255) / 256, 256, 0, stream>>>(ei, E, N, cursor, col);

    int gblocks = (N + 3) / 4;
    int rblocks = (N + 63) / 64;

    // ---- layer 1: 128 -> (2 x 64), concat 128, LN+ELU ----
    gemm_tile<128, 128><<<rblocks, 256, 0, stream>>>(x, W1, Hh, N);
    att_red<2, 64><<<(2 * N + 3) / 4, 256, 0, stream>>>(Hh, as1, ad1, a_s, a_d, N);
    gat_gather<2, 64, 0><<<gblocks, 256, 0, stream>>>(col, row_start, cnt, Hh, a_s, a_d,
                                                      b1, g1, be1, feat, N);

    // ---- layer 2: 128 -> (2 x 32), concat 64, LN+ELU ----
    gemm_tile<128, 64><<<rblocks, 128, 0, stream>>>(feat, W2, Hh, N);
    att_red<2, 32><<<gblocks, 256, 0, stream>>>(Hh, as2, ad2, a_s, a_d, N);
    gat_gather<2, 32, 0><<<gblocks, 256, 0, stream>>>(col, row_start, cnt, Hh, a_s, a_d,
                                                      b2, g2, be2, feat, N);

    // ---- layer 3: 64 -> (1 x 2), bias + log_softmax ----
    l3_transform<<<(N + 255) / 256, 256, 0, stream>>>(feat, W3, as3, ad3, Hh, a_s, a_d, N);
    gat_gather<1, 2, 1><<<gblocks, 256, 0, stream>>>(col, row_start, cnt, Hh, a_s, a_d,
                                                     b3, nullptr, nullptr, (float*)d_out, N);
}

// Round 7
// 289.292 us; speedup vs baseline: 4.5597x; 1.2471x over previous
//
#include <hip/hip_runtime.h>
#include <hip/hip_fp16.h>
#include <math.h>

#define LN_EPS 1e-5f
#define NEG_SLOPE 0.2f

// ---------------- CSR build ----------------

__global__ void hist_kernel(const int* __restrict__ ei, int E, int N, int* __restrict__ cnt) {
    int e = blockIdx.x * blockDim.x + threadIdx.x;
    if (e >= E + N) return;
    int d = (e < E) ? ei[E + e] : (e - E);
    atomicAdd(&cnt[d], 1);
}

__global__ void scan1_kernel(const int* __restrict__ cnt, int* __restrict__ partial,
                             int* __restrict__ bsum, int N) {
    __shared__ int sh[512];
    int t = threadIdx.x;
    int i = blockIdx.x * 512 + t;
    int v = (i < N) ? cnt[i] : 0;
    sh[t] = v;
    __syncthreads();
    for (int off = 1; off < 512; off <<= 1) {
        int a = (t >= off) ? sh[t - off] : 0;
        __syncthreads();
        sh[t] += a;
        __syncthreads();
    }
    if (i < N) partial[i] = sh[t];
    if (t == 511) bsum[blockIdx.x] = sh[511];
}

__global__ void scan2_kernel(int* __restrict__ bsum, int nb) {
    __shared__ int sh[512];
    int t = threadIdx.x;
    int v = (t < nb) ? bsum[t] : 0;
    sh[t] = v;
    __syncthreads();
    for (int off = 1; off < 512; off <<= 1) {
        int a = (t >= off) ? sh[t - off] : 0;
        __syncthreads();
        sh[t] += a;
        __syncthreads();
    }
    if (t < nb) bsum[t] = sh[t] - v;
}

__global__ void scan3_kernel(const int* __restrict__ partial, const int* __restrict__ boff,
                             const int* __restrict__ cnt, int* __restrict__ row_start,
                             int* __restrict__ cursor, int N) {
    int i = blockIdx.x * blockDim.x + threadIdx.x;
    if (i >= N) return;
    int incl = partial[i] + boff[i >> 9];
    int st = incl - cnt[i];
    row_start[i] = st;
    cursor[i] = st;
}

__global__ void scatter_kernel(const int* __restrict__ ei, int E, int N,
                               int* __restrict__ cursor, int* __restrict__ col) {
    int e = blockIdx.x * blockDim.x + threadIdx.x;
    if (e >= E + N) return;
    int s = (e < E) ? ei[e] : (e - E);
    int d = (e < E) ? ei[E + e] : (e - E);
    int pos = atomicAdd(&cursor[d], 1);
    col[pos] = s;
}

// ---------------- register-tiled GEMM: Yh[N,M] = half(X[N,K] @ W[K,M]) ----------------
template <int K, int M>
__launch_bounds__(256)
__global__ void gemm_tile(const float* __restrict__ X, const float* __restrict__ W,
                          __half* __restrict__ Yh, int N) {
    constexpr int BR = 64, CT = 4, RT = 8, KC = 64;
    constexpr int TC = M / CT;
    constexpr int NT = TC * (BR / RT);
    __shared__ float Xs[BR][KC];
    __shared__ float Ws[KC][M];
    int tid = threadIdx.x;
    if (tid >= NT) return;
    int tc = tid % TC, tr = tid / TC;
    int row0 = blockIdx.x * BR;
    float acc[RT][CT] = {};
#pragma unroll
    for (int kc = 0; kc < K; kc += KC) {
        constexpr int XV = (BR * KC / 4) / NT;
#pragma unroll
        for (int i = 0; i < XV; ++i) {
            int f = tid + i * NT;
            int r = f / (KC / 4), c4 = f % (KC / 4);
            int row = row0 + r;
            float4 v = (row < N) ? *reinterpret_cast<const float4*>(&X[(size_t)row * K + kc + c4 * 4])
                                 : make_float4(0.f, 0.f, 0.f, 0.f);
            *reinterpret_cast<float4*>(&Xs[r][c4 * 4]) = v;
        }
        constexpr int WV = (KC * M / 4) / NT;
#pragma unroll
        for (int i = 0; i < WV; ++i) {
            int f = tid + i * NT;
            int kk = f / (M / 4), c4 = f % (M / 4);
            *reinterpret_cast<float4*>(&Ws[kk][c4 * 4]) =
                *reinterpret_cast<const float4*>(&W[(size_t)(kc + kk) * M + c4 * 4]);
        }
        __syncthreads();
#pragma unroll 4
        for (int k = 0; k < KC; ++k) {
            float4 wv = *reinterpret_cast<const float4*>(&Ws[k][tc * 4]);
#pragma unroll
            for (int rr = 0; rr < RT; ++rr) {
                float xv = Xs[tr * RT + rr][k];
                acc[rr][0] += xv * wv.x;
                acc[rr][1] += xv * wv.y;
                acc[rr][2] += xv * wv.z;
                acc[rr][3] += xv * wv.w;
            }
        }
        __syncthreads();
    }
#pragma unroll
    for (int rr = 0; rr < RT; ++rr) {
        int row = row0 + tr * RT + rr;
        if (row < N) {
            union { __half2 h[2]; uint2 u; } pk;
            pk.h[0] = __floats2half2_rn(acc[rr][0], acc[rr][1]);
            pk.h[1] = __floats2half2_rn(acc[rr][2], acc[rr][3]);
            *reinterpret_cast<uint2*>(&Yh[(size_t)row * M + tc * 4]) = pk.u;
        }
    }
}

// ---------------- attention logits from half h ----------------
template <int HH, int C>
__launch_bounds__(256)
__global__ void att_red(const __half* __restrict__ Hf, const float* __restrict__ AS,
                        const float* __restrict__ AD, float* __restrict__ a_s,
                        float* __restrict__ a_d, int N) {
    int wid = blockIdx.x * (blockDim.x >> 6) + (threadIdx.x >> 6);
    int lane = threadIdx.x & 63;
    if constexpr (C == 64) {
        int row = wid >> 1, head = wid & 1;
        if (row >= N) return;
        float v = __half2float(Hf[(size_t)row * 128 + head * 64 + lane]);
        float s1 = v * AS[head * 64 + lane];
        float s2 = v * AD[head * 64 + lane];
#pragma unroll
        for (int off = 32; off > 0; off >>= 1) {
            s1 += __shfl_xor(s1, off);
            s2 += __shfl_xor(s2, off);
        }
        if (lane == 0) {
            a_s[row * 2 + head] = s1;
            a_d[row * 2 + head] = s2;
        }
    } else {
        int row = wid;
        if (row >= N) return;
        float v = __half2float(Hf[(size_t)row * 64 + lane]);
        float s1 = v * AS[lane];
        float s2 = v * AD[lane];
#pragma unroll
        for (int off = 16; off > 0; off >>= 1) {
            s1 += __shfl_xor(s1, off);
            s2 += __shfl_xor(s2, off);
        }
        if ((lane & 31) == 0) {
            a_s[row * 2 + (lane >> 5)] = s1;
            a_d[row * 2 + (lane >> 5)] = s2;
        }
    }
}

// ---------------- layer 3 transform ----------------
__launch_bounds__(256)
__global__ void l3_transform(const float* __restrict__ X, const float* __restrict__ W3,
                             const float* __restrict__ as3, const float* __restrict__ ad3,
                             __half* __restrict__ h3h, float* __restrict__ a_s,
                             float* __restrict__ a_d, int N) {
    int n = blockIdx.x * blockDim.x + threadIdx.x;
    if (n >= N) return;
    const float4* xp = reinterpret_cast<const float4*>(&X[(size_t)n * 64]);
    float h0 = 0.f, h1 = 0.f;
#pragma unroll
    for (int i = 0; i < 16; ++i) {
        float4 x4 = xp[i];
        int k = i * 4;
        h0 += x4.x * W3[(k + 0) * 2] + x4.y * W3[(k + 1) * 2] +
              x4.z * W3[(k + 2) * 2] + x4.w * W3[(k + 3) * 2];
        h1 += x4.x * W3[(k + 0) * 2 + 1] + x4.y * W3[(k + 1) * 2 + 1] +
              x4.z * W3[(k + 2) * 2 + 1] + x4.w * W3[(k + 3) * 2 + 1];
    }
    *reinterpret_cast<__half2*>(&h3h[(size_t)n * 2]) = __floats2half2_rn(h0, h1);
    a_s[n] = h0 * as3[0] + h1 * as3[1];
    a_d[n] = h0 * ad3[0] + h1 * ad3[1];
}

// ---------------- fused GAT aggregation: one wave per dst node ----------------
// MODE 0: phase-1 lane-per-edge softmax -> normalized coefs staged in wave-private
//   LDS; phase-2 per-lane-feature gather with manual unroll-4 (independent loads,
//   no cross-lane ops in the loop).  MODE 1 (M=2): lane-per-edge, one shfl tree.
template <int HH, int C, int MODE>
__launch_bounds__(256)
__global__ void gat_gather(const int* __restrict__ col, const int* __restrict__ row_start,
                           const int* __restrict__ cnt, const __half* __restrict__ Hf,
                           const float* __restrict__ a_s, const float* __restrict__ a_d,
                           const float* __restrict__ bias, const float* __restrict__ gw,
                           const float* __restrict__ bw, float* __restrict__ outp, int N) {
    int wid = blockIdx.x * (blockDim.x >> 6) + (threadIdx.x >> 6);
    int lane = threadIdx.x & 63;
    if (wid >= N) return;
    const int d = wid;
    const int start = row_start[d];
    const int deg = cnt[d];

    if constexpr (MODE == 1) {
        float ad0 = a_d[d];
        float m0 = -INFINITY, s0 = 0.f, acc0 = 0.f, acc1 = 0.f;
        if (deg <= 64) {
            int src_l = (lane < deg) ? col[start + lane] : 0;
            float lg0 = -INFINITY;
            if (lane < deg) {
                float v0 = a_s[src_l] + ad0;
                lg0 = (v0 > 0.f) ? v0 : NEG_SLOPE * v0;
            }
            m0 = lg0;
#pragma unroll
            for (int off = 32; off > 0; off >>= 1) m0 = fmaxf(m0, __shfl_xor(m0, off));
            float e0 = 0.f;
            if (lane < deg) {
                e0 = __expf(lg0 - m0);
                float2 f = __half22float2(*reinterpret_cast<const __half2*>(Hf + (size_t)src_l * 2));
                acc0 = e0 * f.x;
                acc1 = e0 * f.y;
            }
            s0 = e0;
#pragma unroll
            for (int off = 32; off > 0; off >>= 1) {
                s0 += __shfl_xor(s0, off);
                acc0 += __shfl_xor(acc0, off);
                acc1 += __shfl_xor(acc1, off);
            }
        } else {
            for (int base = 0; base < deg; base += 64) {
                int j = base + lane;
                if (j < deg) {
                    int src = col[start + j];
                    float v0 = a_s[src] + ad0;
                    v0 = (v0 > 0.f) ? v0 : NEG_SLOPE * v0;
                    float nm = fmaxf(m0, v0);
                    float sc = (m0 == -INFINITY) ? 0.f : __expf(m0 - nm);
                    float e = __expf(v0 - nm);
                    float2 f = __half22float2(*reinterpret_cast<const __half2*>(Hf + (size_t)src * 2));
                    s0 = s0 * sc + e;
                    acc0 = acc0 * sc + e * f.x;
                    acc1 = acc1 * sc + e * f.y;
                    m0 = nm;
                }
            }
#pragma unroll
            for (int off = 32; off > 0; off >>= 1) {
                float om = __shfl_xor(m0, off);
                float os = __shfl_xor(s0, off);
                float oa0 = __shfl_xor(acc0, off);
                float oa1 = __shfl_xor(acc1, off);
                float nm = fmaxf(m0, om);
                float t1 = (m0 == -INFINITY) ? 0.f : __expf(m0 - nm);
                float t2 = (om == -INFINITY) ? 0.f : __expf(om - nm);
                m0 = nm;
                s0 = s0 * t1 + os * t2;
                acc0 = acc0 * t1 + oa0 * t2;
                acc1 = acc1 * t1 + oa1 * t2;
            }
        }
        if (lane == 0) {
            float inv = 1.f / (s0 + 1e-16f);
            float h0 = acc0 * inv + bias[0];
            float h1 = acc1 * inv + bias[1];
            float mx = fmaxf(h0, h1);
            float l = mx + logf(expf(h0 - mx) + expf(h1 - mx));
            *reinterpret_cast<float2*>(outp + (size_t)d * 2) = make_float2(h0 - l, h1 - l);
        }
    }

    if constexpr (MODE == 0) {
        constexpr int M = HH * C;
        constexpr int FPL = (M / 64 > 0) ? (M / 64) : 1;  // 2 (M=128) or 1 (M=64)
        __shared__ int   s_src[4][64];
        __shared__ float s_cf[4][2][64];
        const int wslot = (threadIdx.x >> 6);
        const int t0 = lane * FPL;
        const int hl = lane >> 5;                     // head owning this lane's features

        float ad0 = a_d[d * 2];
        float ad1 = a_d[d * 2 + 1];

        float acc[FPL] = {};

        if (deg <= 64) {
            // phase 1: lane-per-edge softmax, normalized coefs -> LDS
            int src_l = (lane < deg) ? col[start + lane] : 0;
            float lg0 = -INFINITY, lg1 = -INFINITY;
            if (lane < deg) {
                float2 av = *reinterpret_cast<const float2*>(a_s + (size_t)src_l * 2);
                float v0 = av.x + ad0;
                lg0 = (v0 > 0.f) ? v0 : NEG_SLOPE * v0;
                float v1 = av.y + ad1;
                lg1 = (v1 > 0.f) ? v1 : NEG_SLOPE * v1;
            }
            float m0 = lg0, m1 = lg1;
#pragma unroll
            for (int off = 32; off > 0; off >>= 1) {
                m0 = fmaxf(m0, __shfl_xor(m0, off));
                m1 = fmaxf(m1, __shfl_xor(m1, off));
            }
            float e0 = (lane < deg) ? __expf(lg0 - m0) : 0.f;
            float e1 = (lane < deg) ? __expf(lg1 - m1) : 0.f;
            float s0 = e0, s1 = e1;
#pragma unroll
            for (int off = 32; off > 0; off >>= 1) {
                s0 += __shfl_xor(s0, off);
                s1 += __shfl_xor(s1, off);
            }
            float inv0 = 1.f / (s0 + 1e-16f);
            float inv1 = 1.f / (s1 + 1e-16f);
            s_src[wslot][lane] = src_l;
            s_cf[wslot][0][lane] = e0 * inv0;
            s_cf[wslot][1][lane] = e1 * inv1;
            // wave-private LDS: compiler inserts the lgkmcnt wait on the RAW dep

            // phase 2: unroll-4 gather, no cross-lane ops
            const float* cp = &s_cf[wslot][hl][0];
            const int* sp = &s_src[wslot][0];
            int j = 0;
            for (; j + 4 <= deg; j += 4) {
                int i0 = sp[j], i1 = sp[j + 1], i2 = sp[j + 2], i3 = sp[j + 3];
                float c0 = cp[j], c1 = cp[j + 1], c2 = cp[j + 2], c3 = cp[j + 3];
                if constexpr (FPL == 2) {
                    __half2 r0 = *reinterpret_cast<const __half2*>(Hf + (size_t)i0 * M + t0);
                    __half2 r1 = *reinterpret_cast<const __half2*>(Hf + (size_t)i1 * M + t0);
                    __half2 r2 = *reinterpret_cast<const __half2*>(Hf + (size_t)i2 * M + t0);
                    __half2 r3 = *reinterpret_cast<const __half2*>(Hf + (size_t)i3 * M + t0);
                    float2 f0 = __half22float2(r0), f1 = __half22float2(r1);
                    float2 f2 = __half22float2(r2), f3 = __half22float2(r3);
                    acc[0] += c0 * f0.x + c1 * f1.x + c2 * f2.x + c3 * f3.x;
                    acc[1] += c0 * f0.y + c1 * f1.y + c2 * f2.y + c3 * f3.y;
                } else {
                    float f0 = __half2float(Hf[(size_t)i0 * M + t0]);
                    float f1 = __half2float(Hf[(size_t)i1 * M + t0]);
                    float f2 = __half2float(Hf[(size_t)i2 * M + t0]);
                    float f3 = __half2float(Hf[(size_t)i3 * M + t0]);
                    acc[0] += c0 * f0 + c1 * f1 + c2 * f2 + c3 * f3;
                }
            }
            for (; j < deg; ++j) {
                int i0 = sp[j];
                float c0 = cp[j];
                if constexpr (FPL == 2) {
                    float2 f0 = __half22float2(*reinterpret_cast<const __half2*>(Hf + (size_t)i0 * M + t0));
                    acc[0] += c0 * f0.x;
                    acc[1] += c0 * f0.y;
                } else {
                    acc[0] += c0 * __half2float(Hf[(size_t)i0 * M + t0]);
                }
            }
        } else {
            // fallback: pass 1 online (m,s); pass 2 chunked via LDS, same inner loop
            float m0 = -INFINITY, m1 = -INFINITY, s0 = 0.f, s1 = 0.f;
            for (int base = 0; base < deg; base += 64) {
                int j = base + lane;
                if (j < deg) {
                    int src = col[start + j];
                    float2 av = *reinterpret_cast<const float2*>(a_s + (size_t)src * 2);
                    float v0 = av.x + ad0;
                    v0 = (v0 > 0.f) ? v0 : NEG_SLOPE * v0;
                    float nm = fmaxf(m0, v0);
                    s0 = s0 * ((m0 == -INFINITY) ? 0.f : __expf(m0 - nm)) + __expf(v0 - nm);
                    m0 = nm;
                    float v1 = av.y + ad1;
                    v1 = (v1 > 0.f) ? v1 : NEG_SLOPE * v1;
                    float nm1 = fmaxf(m1, v1);
                    s1 = s1 * ((m1 == -INFINITY) ? 0.f : __expf(m1 - nm1)) + __expf(v1 - nm1);
                    m1 = nm1;
                }
            }
#pragma unroll
            for (int off = 32; off > 0; off >>= 1) {
                float om = __shfl_xor(m0, off);
                float os = __shfl_xor(s0, off);
                float nm = fmaxf(m0, om);
                float t1 = (m0 == -INFINITY) ? 0.f : __expf(m0 - nm);
                float t2 = (om == -INFINITY) ? 0.f : __expf(om - nm);
                m0 = nm;
                s0 = s0 * t1 + os * t2;
                float om1 = __shfl_xor(m1, off);
                float os1 = __shfl_xor(s1, off);
                float nm1 = fmaxf(m1, om1);
                float u1 = (m1 == -INFINITY) ? 0.f : __expf(m1 - nm1);
                float u2 = (om1 == -INFINITY) ? 0.f : __expf(om1 - nm1);
                m1 = nm1;
                s1 = s1 * u1 + os1 * u2;
            }
            float inv0 = 1.f / (s0 + 1e-16f);
            float inv1 = 1.f / (s1 + 1e-16f);
            for (int base = 0; base < deg; base += 64) {
                int rem = deg - base;
                int nchunk = (rem < 64) ? rem : 64;
                int j = base + lane;
                int src_l = (lane < nchunk) ? col[start + j] : 0;
                float e0 = 0.f, e1 = 0.f;
                if (lane < nchunk) {
                    float2 av = *reinterpret_cast<const float2*>(a_s + (size_t)src_l * 2);
                    float v0 = av.x + ad0;
                    v0 = (v0 > 0.f) ? v0 : NEG_SLOPE * v0;
                    e0 = __expf(v0 - m0) * inv0;
                    float v1 = av.y + ad1;
                    v1 = (v1 > 0.f) ? v1 : NEG_SLOPE * v1;
                    e1 = __expf(v1 - m1) * inv1;
                }
                s_src[wslot][lane] = src_l;
                s_cf[wslot][0][lane] = e0;
                s_cf[wslot][1][lane] = e1;
                const float* cp = &s_cf[wslot][hl][0];
                const int* sp = &s_src[wslot][0];
                int jj = 0;
                for (; jj + 4 <= nchunk; jj += 4) {
                    int i0 = sp[jj], i1 = sp[jj + 1], i2 = sp[jj + 2], i3 = sp[jj + 3];
                    float c0 = cp[jj], c1 = cp[jj + 1], c2 = cp[jj + 2], c3 = cp[jj + 3];
                    if constexpr (FPL == 2) {
                        __half2 r0 = *reinterpret_cast<const __half2*>(Hf + (size_t)i0 * M + t0);
                        __half2 r1 = *reinterpret_cast<const __half2*>(Hf + (size_t)i1 * M + t0);
                        __half2 r2 = *reinterpret_cast<const __half2*>(Hf + (size_t)i2 * M + t0);
                        __half2 r3 = *reinterpret_cast<const __half2*>(Hf + (size_t)i3 * M + t0);
                        float2 f0 = __half22float2(r0), f1 = __half22float2(r1);
                        float2 f2 = __half22float2(r2), f3 = __half22float2(r3);
                        acc[0] += c0 * f0.x + c1 * f1.x + c2 * f2.x + c3 * f3.x;
                        acc[1] += c0 * f0.y + c1 * f1.y + c2 * f2.y + c3 * f3.y;
                    } else {
                        float f0 = __half2float(Hf[(size_t)i0 * M + t0]);
                        float f1 = __half2float(Hf[(size_t)i1 * M + t0]);
                        float f2 = __half2float(Hf[(size_t)i2 * M + t0]);
                        float f3 = __half2float(Hf[(size_t)i3 * M + t0]);
                        acc[0] += c0 * f0 + c1 * f1 + c2 * f2 + c3 * f3;
                    }
                }
                for (; jj < nchunk; ++jj) {
                    int i0 = sp[jj];
                    float c0 = cp[jj];
                    if constexpr (FPL == 2) {
                        float2 f0 = __half22float2(*reinterpret_cast<const __half2*>(Hf + (size_t)i0 * M + t0));
                        acc[0] += c0 * f0.x;
                        acc[1] += c0 * f0.y;
                    } else {
                        acc[0] += c0 * __half2float(Hf[(size_t)i0 * M + t0]);
                    }
                }
            }
        }

        // epilogue: bias + LayerNorm + ELU (coefs already normalized)
        float v[FPL];
        float ls = 0.f;
#pragma unroll
        for (int jj = 0; jj < FPL; ++jj) {
            v[jj] = acc[jj] + bias[t0 + jj];
            ls += v[jj];
        }
#pragma unroll
        for (int off = 32; off > 0; off >>= 1) ls += __shfl_xor(ls, off);
        float mu = ls * (1.0f / M);
        float lv = 0.f;
#pragma unroll
        for (int jj = 0; jj < FPL; ++jj) {
            float dv = v[jj] - mu;
            lv += dv * dv;
        }
#pragma unroll
        for (int off = 32; off > 0; off >>= 1) lv += __shfl_xor(lv, off);
        float rstd = rsqrtf(lv * (1.0f / M) + LN_EPS);
#pragma unroll
        for (int jj = 0; jj < FPL; ++jj) {
            float y = (v[jj] - mu) * rstd * gw[t0 + jj] + bw[t0 + jj];
            v[jj] = (y > 0.f) ? y : expm1f(y);
        }
        if constexpr (FPL == 2) {
            *reinterpret_cast<float2*>(outp + (size_t)d * M + t0) = make_float2(v[0], v[1]);
        } else {
            outp[(size_t)d * M + t0] = v[0];
        }
    }
}

extern "C" void kernel_launch(void* const* d_in, const int* in_sizes, int n_in,
                              void* d_out, int out_size, void* d_ws, size_t ws_size,
                              hipStream_t stream) {
    const float* x   = (const float*)d_in[0];
    const int*   ei  = (const int*)d_in[1];
    const float* W1  = (const float*)d_in[2];
    const float* as1 = (const float*)d_in[3];
    const float* ad1 = (const float*)d_in[4];
    const float* b1  = (const float*)d_in[5];
    const float* g1  = (const float*)d_in[6];
    const float* be1 = (const float*)d_in[7];
    const float* W2  = (const float*)d_in[8];
    const float* as2 = (const float*)d_in[9];
    const float* ad2 = (const float*)d_in[10];
    const float* b2  = (const float*)d_in[11];
    const float* g2  = (const float*)d_in[12];
    const float* be2 = (const float*)d_in[13];
    const float* W3  = (const float*)d_in[14];
    const float* as3 = (const float*)d_in[15];
    const float* ad3 = (const float*)d_in[16];
    const float* b3  = (const float*)d_in[17];

    int N = in_sizes[0] / 128;
    int E = in_sizes[1] / 2;
    int T = E + N;

    __half* Hh  = (__half*)d_ws;                         // N*128 halfs
    float* feat = (float*)(Hh + (size_t)N * 128);        // N*128 f32
    float* a_s  = feat + (size_t)N * 128;                // N*2
    float* a_d  = a_s + (size_t)N * 2;                   // N*2
    int* cnt       = (int*)(a_d + (size_t)N * 2);        // N
    int* partial   = cnt + N;                            // N
    int* bsum      = partial + N;                        // 512
    int* row_start = bsum + 512;                         // N
    int* cursor    = row_start + N;                      // N
    int* col       = cursor + N;                         // E+N

    // ---- CSR build (dst-grouped, self-loops included) ----
    (void)hipMemsetAsync(cnt, 0, (size_t)N * sizeof(int), stream);
    hist_kernel<<<(T + 255) / 256, 256, 0, stream>>>(ei, E, N, cnt);
    int nb = (N + 511) / 512;
    scan1_kernel<<<nb, 512, 0, stream>>>(cnt, partial, bsum, N);
    scan2_kernel<<<1, 512, 0, stream>>>(bsum, nb);
    scan3_kernel<<<(N + 255) / 256, 256, 0, stream>>>(partial, bsum, cnt, row_start, cursor, N);
    scatter_kernel<<<(T + 255) / 256, 256, 0, stream>>>(ei, E, N, cursor, col);

    int gblocks = (N + 3) / 4;
    int rblocks = (N + 63) / 64;

    // ---- layer 1: 128 -> (2 x 64), concat 128, LN+ELU ----
    gemm_tile<128, 128><<<rblocks, 256, 0, stream>>>(x, W1, Hh, N);
    att_red<2, 64><<<(2 * N + 3) / 4, 256, 0, stream>>>(Hh, as1, ad1, a_s, a_d, N);
    gat_gather<2, 64, 0><<<gblocks, 256, 0, stream>>>(col, row_start, cnt, Hh, a_s, a_d,
                                                      b1, g1, be1, feat, N);

    // ---- layer 2: 128 -> (2 x 32), concat 64, LN+ELU ----
    gemm_tile<128, 64><<<rblocks, 128, 0, stream>>>(feat, W2, Hh, N);
    att_red<2, 32><<<gblocks, 256, 0, stream>>>(Hh, as2, ad2, a_s, a_d, N);
    gat_gather<2, 32, 0><<<gblocks, 256, 0, stream>>>(col, row_start, cnt, Hh, a_s, a_d,
                                                      b2, g2, be2, feat, N);

    // ---- layer 3: 64 -> (1 x 2), bias + log_softmax ----
    l3_transform<<<(N + 255) / 256, 256, 0, stream>>>(feat, W3, as3, ad3, Hh, a_s, a_d, N);
    gat_gather<1, 2, 1><<<gblocks, 256, 0, stream>>>(col, row_start, cnt, Hh, a_s, a_d,
                                                     b3, nullptr, nullptr, (float*)d_out, N);
}

// Round 8
// 275.964 us; speedup vs baseline: 4.7799x; 1.0483x over previous
//
#include <hip/hip_runtime.h>
#include <hip/hip_fp16.h>
#include <math.h>

#define LN_EPS 1e-5f
#define NEG_SLOPE 0.2f

// ---------------- CSR build ----------------
// 4 independent edge-chains per thread: 4 atomic round-trips in flight per wave.

__global__ void hist_kernel(const int* __restrict__ ei, int E, int N, int* __restrict__ cnt) {
    int T = E + N;
    int stride = gridDim.x * blockDim.x;
    int e = blockIdx.x * blockDim.x + threadIdx.x;
#pragma unroll
    for (int u = 0; u < 4; ++u) {
        int ee = e + u * stride;
        if (ee < T) {
            int d = (ee < E) ? ei[E + ee] : (ee - E);
            atomicAdd(&cnt[d], 1);
        }
    }
}

__global__ void scan1_kernel(const int* __restrict__ cnt, int* __restrict__ partial,
                             int* __restrict__ bsum, int N) {
    __shared__ int sh[512];
    int t = threadIdx.x;
    int i = blockIdx.x * 512 + t;
    int v = (i < N) ? cnt[i] : 0;
    sh[t] = v;
    __syncthreads();
    for (int off = 1; off < 512; off <<= 1) {
        int a = (t >= off) ? sh[t - off] : 0;
        __syncthreads();
        sh[t] += a;
        __syncthreads();
    }
    if (i < N) partial[i] = sh[t];
    if (t == 511) bsum[blockIdx.x] = sh[511];
}

__global__ void scan2_kernel(int* __restrict__ bsum, int nb) {
    __shared__ int sh[512];
    int t = threadIdx.x;
    int v = (t < nb) ? bsum[t] : 0;
    sh[t] = v;
    __syncthreads();
    for (int off = 1; off < 512; off <<= 1) {
        int a = (t >= off) ? sh[t - off] : 0;
        __syncthreads();
        sh[t] += a;
        __syncthreads();
    }
    if (t < nb) bsum[t] = sh[t] - v;
}

__global__ void scan3_kernel(const int* __restrict__ partial, const int* __restrict__ boff,
                             const int* __restrict__ cnt, int* __restrict__ row_start,
                             int* __restrict__ cursor, int N) {
    int i = blockIdx.x * blockDim.x + threadIdx.x;
    if (i >= N) return;
    int incl = partial[i] + boff[i >> 9];
    int st = incl - cnt[i];
    row_start[i] = st;
    cursor[i] = st;
}

__global__ void scatter_kernel(const int* __restrict__ ei, int E, int N,
                               int* __restrict__ cursor, int* __restrict__ col) {
    int T = E + N;
    int stride = gridDim.x * blockDim.x;
    int e = blockIdx.x * blockDim.x + threadIdx.x;
    bool ok[4];
    int s[4], d[4], pos[4];
#pragma unroll
    for (int u = 0; u < 4; ++u) {
        int ee = e + u * stride;
        ok[u] = (ee < T);
        int ec = ok[u] ? ee : 0;
        s[u] = (ec < E) ? ei[ec] : (ec - E);
        d[u] = (ec < E) ? ei[E + ec] : (ec - E);
    }
#pragma unroll
    for (int u = 0; u < 4; ++u) {
        if (ok[u]) pos[u] = atomicAdd(&cursor[d[u]], 1);
    }
#pragma unroll
    for (int u = 0; u < 4; ++u) {
        if (ok[u]) col[pos[u]] = s[u];
    }
}

// ---------------- register-tiled GEMM: Yh[N,M] = half(X[N,K] @ W[K,M]) ----------------
template <int K, int M>
__launch_bounds__(256)
__global__ void gemm_tile(const float* __restrict__ X, const float* __restrict__ W,
                          __half* __restrict__ Yh, int N) {
    constexpr int BR = 64, CT = 4, RT = 8, KC = 64;
    constexpr int TC = M / CT;
    constexpr int NT = TC * (BR / RT);
    __shared__ float Xs[BR][KC];
    __shared__ float Ws[KC][M];
    int tid = threadIdx.x;
    if (tid >= NT) return;
    int tc = tid % TC, tr = tid / TC;
    int row0 = blockIdx.x * BR;
    float acc[RT][CT] = {};
#pragma unroll
    for (int kc = 0; kc < K; kc += KC) {
        constexpr int XV = (BR * KC / 4) / NT;
#pragma unroll
        for (int i = 0; i < XV; ++i) {
            int f = tid + i * NT;
            int r = f / (KC / 4), c4 = f % (KC / 4);
            int row = row0 + r;
            float4 v = (row < N) ? *reinterpret_cast<const float4*>(&X[(size_t)row * K + kc + c4 * 4])
                                 : make_float4(0.f, 0.f, 0.f, 0.f);
            *reinterpret_cast<float4*>(&Xs[r][c4 * 4]) = v;
        }
        constexpr int WV = (KC * M / 4) / NT;
#pragma unroll
        for (int i = 0; i < WV; ++i) {
            int f = tid + i * NT;
            int kk = f / (M / 4), c4 = f % (M / 4);
            *reinterpret_cast<float4*>(&Ws[kk][c4 * 4]) =
                *reinterpret_cast<const float4*>(&W[(size_t)(kc + kk) * M + c4 * 4]);
        }
        __syncthreads();
#pragma unroll 4
        for (int k = 0; k < KC; ++k) {
            float4 wv = *reinterpret_cast<const float4*>(&Ws[k][tc * 4]);
#pragma unroll
            for (int rr = 0; rr < RT; ++rr) {
                float xv = Xs[tr * RT + rr][k];
                acc[rr][0] += xv * wv.x;
                acc[rr][1] += xv * wv.y;
                acc[rr][2] += xv * wv.z;
                acc[rr][3] += xv * wv.w;
            }
        }
        __syncthreads();
    }
#pragma unroll
    for (int rr = 0; rr < RT; ++rr) {
        int row = row0 + tr * RT + rr;
        if (row < N) {
            union { __half2 h[2]; uint2 u; } pk;
            pk.h[0] = __floats2half2_rn(acc[rr][0], acc[rr][1]);
            pk.h[1] = __floats2half2_rn(acc[rr][2], acc[rr][3]);
            *reinterpret_cast<uint2*>(&Yh[(size_t)row * M + tc * 4]) = pk.u;
        }
    }
}

// ---------------- attention logits from half h ----------------
template <int HH, int C>
__launch_bounds__(256)
__global__ void att_red(const __half* __restrict__ Hf, const float* __restrict__ AS,
                        const float* __restrict__ AD, float* __restrict__ a_s,
                        float* __restrict__ a_d, int N) {
    int wid = blockIdx.x * (blockDim.x >> 6) + (threadIdx.x >> 6);
    int lane = threadIdx.x & 63;
    if constexpr (C == 64) {
        int row = wid >> 1, head = wid & 1;
        if (row >= N) return;
        float v = __half2float(Hf[(size_t)row * 128 + head * 64 + lane]);
        float s1 = v * AS[head * 64 + lane];
        float s2 = v * AD[head * 64 + lane];
#pragma unroll
        for (int off = 32; off > 0; off >>= 1) {
            s1 += __shfl_xor(s1, off);
            s2 += __shfl_xor(s2, off);
        }
        if (lane == 0) {
            a_s[row * 2 + head] = s1;
            a_d[row * 2 + head] = s2;
        }
    } else {
        int row = wid;
        if (row >= N) return;
        float v = __half2float(Hf[(size_t)row * 64 + lane]);
        float s1 = v * AS[lane];
        float s2 = v * AD[lane];
#pragma unroll
        for (int off = 16; off > 0; off >>= 1) {
            s1 += __shfl_xor(s1, off);
            s2 += __shfl_xor(s2, off);
        }
        if ((lane & 31) == 0) {
            a_s[row * 2 + (lane >> 5)] = s1;
            a_d[row * 2 + (lane >> 5)] = s2;
        }
    }
}

// ---------------- layer 3 transform ----------------
__launch_bounds__(256)
__global__ void l3_transform(const float* __restrict__ X, const float* __restrict__ W3,
                             const float* __restrict__ as3, const float* __restrict__ ad3,
                             __half* __restrict__ h3h, float* __restrict__ a_s,
                             float* __restrict__ a_d, int N) {
    int n = blockIdx.x * blockDim.x + threadIdx.x;
    if (n >= N) return;
    const float4* xp = reinterpret_cast<const float4*>(&X[(size_t)n * 64]);
    float h0 = 0.f, h1 = 0.f;
#pragma unroll
    for (int i = 0; i < 16; ++i) {
        float4 x4 = xp[i];
        int k = i * 4;
        h0 += x4.x * W3[(k + 0) * 2] + x4.y * W3[(k + 1) * 2] +
              x4.z * W3[(k + 2) * 2] + x4.w * W3[(k + 3) * 2];
        h1 += x4.x * W3[(k + 0) * 2 + 1] + x4.y * W3[(k + 1) * 2 + 1] +
              x4.z * W3[(k + 2) * 2 + 1] + x4.w * W3[(k + 3) * 2 + 1];
    }
    *reinterpret_cast<__half2*>(&h3h[(size_t)n * 2]) = __floats2half2_rn(h0, h1);
    a_s[n] = h0 * as3[0] + h1 * as3[1];
    a_d[n] = h0 * ad3[0] + h1 * ad3[1];
}

// ---------------- fused GAT aggregation: one wave per dst node ----------------
template <int HH, int C, int MODE>
__launch_bounds__(256)
__global__ void gat_gather(const int* __restrict__ col, const int* __restrict__ row_start,
                           const int* __restrict__ cnt, const __half* __restrict__ Hf,
                           const float* __restrict__ a_s, const float* __restrict__ a_d,
                           const float* __restrict__ bias, const float* __restrict__ gw,
                           const float* __restrict__ bw, float* __restrict__ outp, int N) {
    int wid = blockIdx.x * (blockDim.x >> 6) + (threadIdx.x >> 6);
    int lane = threadIdx.x & 63;
    if (wid >= N) return;
    const int d = wid;
    const int start = row_start[d];
    const int deg = cnt[d];

    if constexpr (MODE == 1) {
        float ad0 = a_d[d];
        float m0 = -INFINITY, s0 = 0.f, acc0 = 0.f, acc1 = 0.f;
        if (deg <= 64) {
            int src_l = (lane < deg) ? col[start + lane] : 0;
            float lg0 = -INFINITY;
            if (lane < deg) {
                float v0 = a_s[src_l] + ad0;
                lg0 = (v0 > 0.f) ? v0 : NEG_SLOPE * v0;
            }
            m0 = lg0;
#pragma unroll
            for (int off = 32; off > 0; off >>= 1) m0 = fmaxf(m0, __shfl_xor(m0, off));
            float e0 = 0.f;
            if (lane < deg) {
                e0 = __expf(lg0 - m0);
                float2 f = __half22float2(*reinterpret_cast<const __half2*>(Hf + (size_t)src_l * 2));
                acc0 = e0 * f.x;
                acc1 = e0 * f.y;
            }
            s0 = e0;
#pragma unroll
            for (int off = 32; off > 0; off >>= 1) {
                s0 += __shfl_xor(s0, off);
                acc0 += __shfl_xor(acc0, off);
                acc1 += __shfl_xor(acc1, off);
            }
        } else {
            for (int base = 0; base < deg; base += 64) {
                int j = base + lane;
                if (j < deg) {
                    int src = col[start + j];
                    float v0 = a_s[src] + ad0;
                    v0 = (v0 > 0.f) ? v0 : NEG_SLOPE * v0;
                    float nm = fmaxf(m0, v0);
                    float sc = (m0 == -INFINITY) ? 0.f : __expf(m0 - nm);
                    float e = __expf(v0 - nm);
                    float2 f = __half22float2(*reinterpret_cast<const __half2*>(Hf + (size_t)src * 2));
                    s0 = s0 * sc + e;
                    acc0 = acc0 * sc + e * f.x;
                    acc1 = acc1 * sc + e * f.y;
                    m0 = nm;
                }
            }
#pragma unroll
            for (int off = 32; off > 0; off >>= 1) {
                float om = __shfl_xor(m0, off);
                float os = __shfl_xor(s0, off);
                float oa0 = __shfl_xor(acc0, off);
                float oa1 = __shfl_xor(acc1, off);
                float nm = fmaxf(m0, om);
                float t1 = (m0 == -INFINITY) ? 0.f : __expf(m0 - nm);
                float t2 = (om == -INFINITY) ? 0.f : __expf(om - nm);
                m0 = nm;
                s0 = s0 * t1 + os * t2;
                acc0 = acc0 * t1 + oa0 * t2;
                acc1 = acc1 * t1 + oa1 * t2;
            }
        }
        if (lane == 0) {
            float inv = 1.f / (s0 + 1e-16f);
            float h0 = acc0 * inv + bias[0];
            float h1 = acc1 * inv + bias[1];
            float mx = fmaxf(h0, h1);
            float l = mx + logf(expf(h0 - mx) + expf(h1 - mx));
            *reinterpret_cast<float2*>(outp + (size_t)d * 2) = make_float2(h0 - l, h1 - l);
        }
    }

    if constexpr (MODE == 0) {
        constexpr int M = HH * C;
        constexpr int FPL = (M / 64 > 0) ? (M / 64) : 1;  // 2 (M=128) or 1 (M=64)
        __shared__ int   s_src[4][64];
        __shared__ float s_cf[4][2][64];
        const int wslot = (threadIdx.x >> 6);
        const int t0 = lane * FPL;
        const int hl = lane >> 5;                     // head owning this lane's features

        float ad0 = a_d[d * 2];
        float ad1 = a_d[d * 2 + 1];

        float acc[FPL] = {};

        if (deg <= 64) {
            int src_l = (lane < deg) ? col[start + lane] : 0;
            float lg0 = -INFINITY, lg1 = -INFINITY;
            if (lane < deg) {
                float2 av = *reinterpret_cast<const float2*>(a_s + (size_t)src_l * 2);
                float v0 = av.x + ad0;
                lg0 = (v0 > 0.f) ? v0 : NEG_SLOPE * v0;
                float v1 = av.y + ad1;
                lg1 = (v1 > 0.f) ? v1 : NEG_SLOPE * v1;
            }
            float m0 = lg0, m1 = lg1;
#pragma unroll
            for (int off = 32; off > 0; off >>= 1) {
                m0 = fmaxf(m0, __shfl_xor(m0, off));
                m1 = fmaxf(m1, __shfl_xor(m1, off));
            }
            float e0 = (lane < deg) ? __expf(lg0 - m0) : 0.f;
            float e1 = (lane < deg) ? __expf(lg1 - m1) : 0.f;
            float s0 = e0, s1 = e1;
#pragma unroll
            for (int off = 32; off > 0; off >>= 1) {
                s0 += __shfl_xor(s0, off);
                s1 += __shfl_xor(s1, off);
            }
            float inv0 = 1.f / (s0 + 1e-16f);
            float inv1 = 1.f / (s1 + 1e-16f);
            s_src[wslot][lane] = src_l;
            s_cf[wslot][0][lane] = e0 * inv0;
            s_cf[wslot][1][lane] = e1 * inv1;

            const float* cp = &s_cf[wslot][hl][0];
            const int* sp = &s_src[wslot][0];
            int j = 0;
            for (; j + 4 <= deg; j += 4) {
                int i0 = sp[j], i1 = sp[j + 1], i2 = sp[j + 2], i3 = sp[j + 3];
                float c0 = cp[j], c1 = cp[j + 1], c2 = cp[j + 2], c3 = cp[j + 3];
                if constexpr (FPL == 2) {
                    __half2 r0 = *reinterpret_cast<const __half2*>(Hf + (size_t)i0 * M + t0);
                    __half2 r1 = *reinterpret_cast<const __half2*>(Hf + (size_t)i1 * M + t0);
                    __half2 r2 = *reinterpret_cast<const __half2*>(Hf + (size_t)i2 * M + t0);
                    __half2 r3 = *reinterpret_cast<const __half2*>(Hf + (size_t)i3 * M + t0);
                    float2 f0 = __half22float2(r0), f1 = __half22float2(r1);
                    float2 f2 = __half22float2(r2), f3 = __half22float2(r3);
                    acc[0] += c0 * f0.x + c1 * f1.x + c2 * f2.x + c3 * f3.x;
                    acc[1] += c0 * f0.y + c1 * f1.y + c2 * f2.y + c3 * f3.y;
                } else {
                    float f0 = __half2float(Hf[(size_t)i0 * M + t0]);
                    float f1 = __half2float(Hf[(size_t)i1 * M + t0]);
                    float f2 = __half2float(Hf[(size_t)i2 * M + t0]);
                    float f3 = __half2float(Hf[(size_t)i3 * M + t0]);
                    acc[0] += c0 * f0 + c1 * f1 + c2 * f2 + c3 * f3;
                }
            }
            for (; j < deg; ++j) {
                int i0 = sp[j];
                float c0 = cp[j];
                if constexpr (FPL == 2) {
                    float2 f0 = __half22float2(*reinterpret_cast<const __half2*>(Hf + (size_t)i0 * M + t0));
                    acc[0] += c0 * f0.x;
                    acc[1] += c0 * f0.y;
                } else {
                    acc[0] += c0 * __half2float(Hf[(size_t)i0 * M + t0]);
                }
            }
        } else {
            float m0 = -INFINITY, m1 = -INFINITY, s0 = 0.f, s1 = 0.f;
            for (int base = 0; base < deg; base += 64) {
                int j = base + lane;
                if (j < deg) {
                    int src = col[start + j];
                    float2 av = *reinterpret_cast<const float2*>(a_s + (size_t)src * 2);
                    float v0 = av.x + ad0;
                    v0 = (v0 > 0.f) ? v0 : NEG_SLOPE * v0;
                    float nm = fmaxf(m0, v0);
                    s0 = s0 * ((m0 == -INFINITY) ? 0.f : __expf(m0 - nm)) + __expf(v0 - nm);
                    m0 = nm;
                    float v1 = av.y + ad1;
                    v1 = (v1 > 0.f) ? v1 : NEG_SLOPE * v1;
                    float nm1 = fmaxf(m1, v1);
                    s1 = s1 * ((m1 == -INFINITY) ? 0.f : __expf(m1 - nm1)) + __expf(v1 - nm1);
                    m1 = nm1;
                }
            }
#pragma unroll
            for (int off = 32; off > 0; off >>= 1) {
                float om = __shfl_xor(m0, off);
                float os = __shfl_xor(s0, off);
                float nm = fmaxf(m0, om);
                float t1 = (m0 == -INFINITY) ? 0.f : __expf(m0 - nm);
                float t2 = (om == -INFINITY) ? 0.f : __expf(om - nm);
                m0 = nm;
                s0 = s0 * t1 + os * t2;
                float om1 = __shfl_xor(m1, off);
                float os1 = __shfl_xor(s1, off);
                float nm1 = fmaxf(m1, om1);
                float u1 = (m1 == -INFINITY) ? 0.f : __expf(m1 - nm1);
                float u2 = (om1 == -INFINITY) ? 0.f : __expf(om1 - nm1);
                m1 = nm1;
                s1 = s1 * u1 + os1 * u2;
            }
            float inv0 = 1.f / (s0 + 1e-16f);
            float inv1 = 1.f / (s1 + 1e-16f);
            for (int base = 0; base < deg; base += 64) {
                int rem = deg - base;
                int nchunk = (rem < 64) ? rem : 64;
                int j = base + lane;
                int src_l = (lane < nchunk) ? col[start + j] : 0;
                float e0 = 0.f, e1 = 0.f;
                if (lane < nchunk) {
                    float2 av = *reinterpret_cast<const float2*>(a_s + (size_t)src_l * 2);
                    float v0 = av.x + ad0;
                    v0 = (v0 > 0.f) ? v0 : NEG_SLOPE * v0;
                    e0 = __expf(v0 - m0) * inv0;
                    float v1 = av.y + ad1;
                    v1 = (v1 > 0.f) ? v1 : NEG_SLOPE * v1;
                    e1 = __expf(v1 - m1) * inv1;
                }
                s_src[wslot][lane] = src_l;
                s_cf[wslot][0][lane] = e0;
                s_cf[wslot][1][lane] = e1;
                const float* cp = &s_cf[wslot][hl][0];
                const int* sp = &s_src[wslot][0];
                int jj = 0;
                for (; jj + 4 <= nchunk; jj += 4) {
                    int i0 = sp[jj], i1 = sp[jj + 1], i2 = sp[jj + 2], i3 = sp[jj + 3];
                    float c0 = cp[jj], c1 = cp[jj + 1], c2 = cp[jj + 2], c3 = cp[jj + 3];
                    if constexpr (FPL == 2) {
                        __half2 r0 = *reinterpret_cast<const __half2*>(Hf + (size_t)i0 * M + t0);
                        __half2 r1 = *reinterpret_cast<const __half2*>(Hf + (size_t)i1 * M + t0);
                        __half2 r2 = *reinterpret_cast<const __half2*>(Hf + (size_t)i2 * M + t0);
                        __half2 r3 = *reinterpret_cast<const __half2*>(Hf + (size_t)i3 * M + t0);
                        float2 f0 = __half22float2(r0), f1 = __half22float2(r1);
                        float2 f2 = __half22float2(r2), f3 = __half22float2(r3);
                        acc[0] += c0 * f0.x + c1 * f1.x + c2 * f2.x + c3 * f3.x;
                        acc[1] += c0 * f0.y + c1 * f1.y + c2 * f2.y + c3 * f3.y;
                    } else {
                        float f0 = __half2float(Hf[(size_t)i0 * M + t0]);
                        float f1 = __half2float(Hf[(size_t)i1 * M + t0]);
                        float f2 = __half2float(Hf[(size_t)i2 * M + t0]);
                        float f3 = __half2float(Hf[(size_t)i3 * M + t0]);
                        acc[0] += c0 * f0 + c1 * f1 + c2 * f2 + c3 * f3;
                    }
                }
                for (; jj < nchunk; ++jj) {
                    int i0 = sp[jj];
                    float c0 = cp[jj];
                    if constexpr (FPL == 2) {
                        float2 f0 = __half22float2(*reinterpret_cast<const __half2*>(Hf + (size_t)i0 * M + t0));
                        acc[0] += c0 * f0.x;
                        acc[1] += c0 * f0.y;
                    } else {
                        acc[0] += c0 * __half2float(Hf[(size_t)i0 * M + t0]);
                    }
                }
            }
        }

        // epilogue: bias + LayerNorm + ELU (coefs already normalized)
        float v[FPL];
        float ls = 0.f;
#pragma unroll
        for (int jj = 0; jj < FPL; ++jj) {
            v[jj] = acc[jj] + bias[t0 + jj];
            ls += v[jj];
        }
#pragma unroll
        for (int off = 32; off > 0; off >>= 1) ls += __shfl_xor(ls, off);
        float mu = ls * (1.0f / M);
        float lv = 0.f;
#pragma unroll
        for (int jj = 0; jj < FPL; ++jj) {
            float dv = v[jj] - mu;
            lv += dv * dv;
        }
#pragma unroll
        for (int off = 32; off > 0; off >>= 1) lv += __shfl_xor(lv, off);
        float rstd = rsqrtf(lv * (1.0f / M) + LN_EPS);
#pragma unroll
        for (int jj = 0; jj < FPL; ++jj) {
            float y = (v[jj] - mu) * rstd * gw[t0 + jj] + bw[t0 + jj];
            v[jj] = (y > 0.f) ? y : expm1f(y);
        }
        if constexpr (FPL == 2) {
            *reinterpret_cast<float2*>(outp + (size_t)d * M + t0) = make_float2(v[0], v[1]);
        } else {
            outp[(size_t)d * M + t0] = v[0];
        }
    }
}

extern "C" void kernel_launch(void* const* d_in, const int* in_sizes, int n_in,
                              void* d_out, int out_size, void* d_ws, size_t ws_size,
                              hipStream_t stream) {
    const float* x   = (const float*)d_in[0];
    const int*   ei  = (const int*)d_in[1];
    const float* W1  = (const float*)d_in[2];
    const float* as1 = (const float*)d_in[3];
    const float* ad1 = (const float*)d_in[4];
    const float* b1  = (const float*)d_in[5];
    const float* g1  = (const float*)d_in[6];
    const float* be1 = (const float*)d_in[7];
    const float* W2  = (const float*)d_in[8];
    const float* as2 = (const float*)d_in[9];
    const float* ad2 = (const float*)d_in[10];
    const float* b2  = (const float*)d_in[11];
    const float* g2  = (const float*)d_in[12];
    const float* be2 = (const float*)d_in[13];
    const float* W3  = (const float*)d_in[14];
    const float* as3 = (const float*)d_in[15];
    const float* ad3 = (const float*)d_in[16];
    const float* b3  = (const float*)d_in[17];

    int N = in_sizes[0] / 128;
    int E = in_sizes[1] / 2;
    int T = E + N;

    __half* Hh  = (__half*)d_ws;                         // N*128 halfs
    float* feat = (float*)(Hh + (size_t)N * 128);        // N*128 f32
    float* a_s  = feat + (size_t)N * 128;                // N*2
    float* a_d  = a_s + (size_t)N * 2;                   // N*2
    int* cnt       = (int*)(a_d + (size_t)N * 2);        // N
    int* partial   = cnt + N;                            // N
    int* bsum      = partial + N;                        // 512
    int* row_start = bsum + 512;                         // N
    int* cursor    = row_start + N;                      // N
    int* col       = cursor + N;                         // E+N

    // ---- CSR build (dst-grouped, self-loops included) ----
    (void)hipMemsetAsync(cnt, 0, (size_t)N * sizeof(int), stream);
    int ublocks = (T + 1023) / 1024;  // 4 edges per thread
    hist_kernel<<<ublocks, 256, 0, stream>>>(ei, E, N, cnt);
    int nb = (N + 511) / 512;
    scan1_kernel<<<nb, 512, 0, stream>>>(cnt, partial, bsum, N);
    scan2_kernel<<<1, 512, 0, stream>>>(bsum, nb);
    scan3_kernel<<<(N + 255) / 256, 256, 0, stream>>>(partial, bsum, cnt, row_start, cursor, N);
    scatter_kernel<<<ublocks, 256, 0, stream>>>(ei, E, N, cursor, col);

    int gblocks = (N + 3) / 4;
    int rblocks = (N + 63) / 64;

    // ---- layer 1: 128 -> (2 x 64), concat 128, LN+ELU ----
    gemm_tile<128, 128><<<rblocks, 256, 0, stream>>>(x, W1, Hh, N);
    att_red<2, 64><<<(2 * N + 3) / 4, 256, 0, stream>>>(Hh, as1, ad1, a_s, a_d, N);
    gat_gather<2, 64, 0><<<gblocks, 256, 0, stream>>>(col, row_start, cnt, Hh, a_s, a_d,
                                                      b1, g1, be1, feat, N);

    // ---- layer 2: 128 -> (2 x 32), concat 64, LN+ELU ----
    gemm_tile<128, 64><<<rblocks, 128, 0, stream>>>(feat, W2, Hh, N);
    att_red<2, 32><<<gblocks, 256, 0, stream>>>(Hh, as2, ad2, a_s, a_d, N);
    gat_gather<2, 32, 0><<<gblocks, 256, 0, stream>>>(col, row_start, cnt, Hh, a_s, a_d,
                                                      b2, g2, be2, feat, N);

    // ---- layer 3: 64 -> (1 x 2), bias + log_softmax ----
    l3_transform<<<(N + 255) / 256, 256, 0, stream>>>(feat, W3, as3, ad3, Hh, a_s, a_d, N);
    gat_gather<1, 2, 1><<<gblocks, 256, 0, stream>>>(col, row_start, cnt, Hh, a_s, a_d,
                                                     b3, nullptr, nullptr, (float*)d_out, N);
}